// Round 1
// baseline (1356.874 us; speedup 1.0000x reference)
//
#include <hip/hip_runtime.h>

#define NN   65536      // total nodes
#define EE   2097152    // edges
#define HID  32
#define KCH  5
#define OUTS 33
#define NG   8
#define GSZ  262144     // INPUT_SIZE * HIDDEN per graph

// ---------------- degree histograms ----------------
__global__ __launch_bounds__(256) void k_hist(const int* __restrict__ ei,
                                              int* __restrict__ deg,
                                              int* __restrict__ indeg) {
    int e = blockIdx.x * 256 + threadIdx.x;
    atomicAdd(&deg[ei[e]], 1);          // out-degree by src (matches segment_sum over src)
    atomicAdd(&indeg[ei[EE + e]], 1);   // in-degree by dst for CSR build
}

__global__ __launch_bounds__(256) void k_dinv(const int* __restrict__ deg,
                                              float* __restrict__ dinv) {
    int i = blockIdx.x * 256 + threadIdx.x;
    int d = deg[i];
    dinv[i] = d > 0 ? 1.0f / sqrtf((float)d) : 0.0f;
}

// ---------------- single-block exclusive scan over 65536 ints ----------------
__global__ __launch_bounds__(1024) void k_scan(const int* __restrict__ indeg,
                                               int* __restrict__ row_ptr,
                                               int* __restrict__ cursor) {
    __shared__ int s[1024];
    __shared__ int carry;
    int tid = threadIdx.x;
    if (tid == 0) carry = 0;
    __syncthreads();
    for (int c = 0; c < NN; c += 1024) {
        int v = indeg[c + tid];
        s[tid] = v;
        __syncthreads();
        for (int off = 1; off < 1024; off <<= 1) {
            int t = (tid >= off) ? s[tid - off] : 0;
            __syncthreads();
            s[tid] += t;
            __syncthreads();
        }
        int inc  = s[tid];
        int base = carry;
        __syncthreads();
        row_ptr[c + tid + 1] = base + inc;
        cursor[c + tid]      = base + inc - v;   // exclusive + carry
        if (tid == 1023) carry = base + inc;
        __syncthreads();
    }
    if (tid == 0) row_ptr[0] = 0;
}

// ---------------- scatter edges into CSR, pack (src, norm) ----------------
__global__ __launch_bounds__(256) void k_scatter(const int* __restrict__ ei,
                                                 const float* __restrict__ dinv,
                                                 int* __restrict__ cursor,
                                                 int2* __restrict__ ep) {
    int e = blockIdx.x * 256 + threadIdx.x;
    int s = ei[e], d = ei[EE + e];
    int pos = atomicAdd(&cursor[d], 1);
    float nr = -(dinv[s] * dinv[d]);
    ep[pos] = make_int2(s, __float_as_int(nr));
}

// ---------------- width-1 propagation (layer 1) ----------------
__global__ __launch_bounds__(256) void k_prop1(const int* __restrict__ row_ptr,
                                               const int2* __restrict__ ep,
                                               const float* __restrict__ tin,
                                               const float* __restrict__ prev,
                                               float* __restrict__ tout,
                                               float alpha) {
    int n = blockIdx.x * 256 + threadIdx.x;
    int e0 = row_ptr[n], e1 = row_ptr[n + 1];
    float a0 = 0.f, a1 = 0.f;
    int e = e0;
    for (; e + 1 < e1; e += 2) {
        int2 p0 = ep[e], p1 = ep[e + 1];
        a0 += __int_as_float(p0.y) * tin[p0.x];
        a1 += __int_as_float(p1.y) * tin[p1.x];
    }
    if (e < e1) { int2 p = ep[e]; a0 += __int_as_float(p.y) * tin[p.x]; }
    float r = alpha * (a0 + a1);
    if (prev) r -= prev[n];
    tout[n] = r;
}

// ---------------- width-32 propagation: 32 lanes per node, lane = feature ----
__global__ __launch_bounds__(256) void k_prop32(const int* __restrict__ row_ptr,
                                                const int2* __restrict__ ep,
                                                const float* __restrict__ tin,
                                                const float* __restrict__ prev,
                                                float* __restrict__ tout,
                                                float alpha) {
    int idx = blockIdx.x * 256 + threadIdx.x;
    int n = idx >> 5, j = idx & 31;
    int e0 = row_ptr[n], e1 = row_ptr[n + 1];
    float a0 = 0.f, a1 = 0.f;
    int e = e0;
    for (; e + 1 < e1; e += 2) {
        int2 p0 = ep[e], p1 = ep[e + 1];
        a0 += __int_as_float(p0.y) * tin[(p0.x << 5) + j];
        a1 += __int_as_float(p1.y) * tin[(p1.x << 5) + j];
    }
    if (e < e1) { int2 p = ep[e]; a0 += __int_as_float(p.y) * tin[(p.x << 5) + j]; }
    float r = alpha * (a0 + a1);
    if (prev) r -= prev[idx];
    tout[idx] = r;
}

// ---------------- layer-1 combine: h = relu(sum_k tx_k * W1[k] + b1) --------
__global__ __launch_bounds__(256) void k_comb1(const float* __restrict__ tx,
                                               const float* __restrict__ W,
                                               const float* __restrict__ b,
                                               float* __restrict__ hout) {
    int idx = blockIdx.x * 256 + threadIdx.x;
    int n = idx >> 5, j = idx & 31;
    float acc = b[j];
#pragma unroll
    for (int k = 0; k < KCH; ++k)
        acc += tx[k * NN + n] * W[k * HID + j];
    hout[idx] = fmaxf(acc, 0.f);
}

// ---------------- 32-wide combine: h = act(sum_k tx_k @ W[k] + b) -----------
__global__ __launch_bounds__(256) void k_comb32(const float* __restrict__ tx,
                                                const float* __restrict__ W,
                                                const float* __restrict__ b,
                                                float* __restrict__ hout,
                                                int relu) {
    __shared__ float Ws[KCH * HID * HID];
    int tid = threadIdx.x;
    for (int t = tid; t < KCH * HID * HID; t += 256) Ws[t] = W[t];
    __syncthreads();
    int idx = blockIdx.x * 256 + tid;
    int n = idx >> 5, j = idx & 31;
    int lane = tid & 63;
    int base_lane = lane & 32;          // start of this node's 32-lane group in the wave
    float acc = b[j];
#pragma unroll
    for (int k = 0; k < KCH; ++k) {
        float vk = tx[(size_t)k * NN * HID + (n << 5) + j];
#pragma unroll
        for (int i = 0; i < HID; ++i) {
            float a = __shfl(vk, base_lane + i, 64);   // broadcast tx[k][n][i]
            acc += a * Ws[(k * HID + i) * HID + j];
        }
    }
    hout[idx] = relu ? fmaxf(acc, 0.f) : acc;
}

// ---------------- readout ----------------
__global__ void k_initout(const float* __restrict__ bl, float* __restrict__ out) {
    int i = blockIdx.x * 64 + threadIdx.x;
    if (i < NG * OUTS) out[i] = bl[i % OUTS];
}

__global__ __launch_bounds__(256) void k_readout(const float* __restrict__ h,
                                                 const float* __restrict__ Wl,
                                                 float* __restrict__ out) {
    int g = blockIdx.x >> 4, bi = blockIdx.x & 15;
    int tid = threadIdx.x;
    float acc[OUTS];
#pragma unroll
    for (int o = 0; o < OUTS; ++o) acc[o] = 0.f;
    const float* hg = h + (size_t)g * GSZ;
    for (int it = 0; it < 64; ++it) {
        int m = (bi * 64 + it) * 256 + tid;
        float hv = hg[m];
        const float* wr = Wl + (size_t)m * OUTS;
#pragma unroll
        for (int o = 0; o < OUTS; ++o) acc[o] += hv * wr[o];
    }
#pragma unroll
    for (int o = 0; o < OUTS; ++o) {
        float v = acc[o];
        for (int off = 32; off > 0; off >>= 1) v += __shfl_down(v, off, 64);
        if ((tid & 63) == 0) atomicAdd(&out[g * OUTS + o], v);
    }
}

extern "C" void kernel_launch(void* const* d_in, const int* in_sizes, int n_in,
                              void* d_out, int out_size, void* d_ws, size_t ws_size,
                              hipStream_t stream) {
    const float* x  = (const float*)d_in[0];
    const int*   ei = (const int*)d_in[1];
    // d_in[2] = batch (unused: graphs are fixed contiguous 8192-node chunks)
    const float* W1 = (const float*)d_in[3];
    const float* b1 = (const float*)d_in[4];
    const float* W2 = (const float*)d_in[5];
    const float* b2 = (const float*)d_in[6];
    const float* W3 = (const float*)d_in[7];
    const float* b3 = (const float*)d_in[8];
    const float* Wl = (const float*)d_in[9];
    const float* bl = (const float*)d_in[10];
    float* out = (float*)d_out;

    char* ws = (char*)d_ws;
    size_t off = 0;
    auto alloc = [&](size_t bytes) -> void* {
        void* p = ws + off;
        off += (bytes + 255) & ~(size_t)255;
        return p;
    };
    int*   deg    = (int*)alloc((size_t)NN * 4);
    int*   indeg  = (int*)alloc((size_t)NN * 4);
    int*   rowp   = (int*)alloc((size_t)(NN + 1) * 4);
    int*   cursor = (int*)alloc((size_t)NN * 4);
    float* dinv   = (float*)alloc((size_t)NN * 4);
    int2*  ep     = (int2*)alloc((size_t)EE * 8);
    float* txw1   = (float*)alloc((size_t)KCH * NN * 4);
    float* tx32   = (float*)alloc((size_t)KCH * NN * HID * 4);
    float* h_a    = (float*)alloc((size_t)NN * HID * 4);
    float* h_b    = (float*)alloc((size_t)NN * HID * 4);

    hipMemsetAsync(deg,   0, (size_t)NN * 4, stream);
    hipMemsetAsync(indeg, 0, (size_t)NN * 4, stream);
    k_hist<<<EE / 256, 256, 0, stream>>>(ei, deg, indeg);
    k_dinv<<<NN / 256, 256, 0, stream>>>(deg, dinv);
    k_scan<<<1, 1024, 0, stream>>>(indeg, rowp, cursor);
    k_scatter<<<EE / 256, 256, 0, stream>>>(ei, dinv, cursor, ep);

    // ---- layer 1 (width 1 input) ----
    hipMemcpyAsync(txw1, x, (size_t)NN * 4, hipMemcpyDeviceToDevice, stream);
    k_prop1<<<NN / 256, 256, 0, stream>>>(rowp, ep, txw1,          nullptr,       txw1 + 1 * NN, 1.f);
    k_prop1<<<NN / 256, 256, 0, stream>>>(rowp, ep, txw1 + 1 * NN, txw1,          txw1 + 2 * NN, 2.f);
    k_prop1<<<NN / 256, 256, 0, stream>>>(rowp, ep, txw1 + 2 * NN, txw1 + 1 * NN, txw1 + 3 * NN, 2.f);
    k_prop1<<<NN / 256, 256, 0, stream>>>(rowp, ep, txw1 + 3 * NN, txw1 + 2 * NN, txw1 + 4 * NN, 2.f);
    k_comb1<<<(NN * HID) / 256, 256, 0, stream>>>(txw1, W1, b1, h_a);

    const size_t S = (size_t)NN * HID;
    // ---- layer 2 ----
    hipMemcpyAsync(tx32, h_a, S * 4, hipMemcpyDeviceToDevice, stream);
    k_prop32<<<S / 256, 256, 0, stream>>>(rowp, ep, tx32,         nullptr,      tx32 + 1 * S, 1.f);
    k_prop32<<<S / 256, 256, 0, stream>>>(rowp, ep, tx32 + 1 * S, tx32,         tx32 + 2 * S, 2.f);
    k_prop32<<<S / 256, 256, 0, stream>>>(rowp, ep, tx32 + 2 * S, tx32 + 1 * S, tx32 + 3 * S, 2.f);
    k_prop32<<<S / 256, 256, 0, stream>>>(rowp, ep, tx32 + 3 * S, tx32 + 2 * S, tx32 + 4 * S, 2.f);
    k_comb32<<<S / 256, 256, 0, stream>>>(tx32, W2, b2, h_b, 1);

    // ---- layer 3 (no relu) ----
    hipMemcpyAsync(tx32, h_b, S * 4, hipMemcpyDeviceToDevice, stream);
    k_prop32<<<S / 256, 256, 0, stream>>>(rowp, ep, tx32,         nullptr,      tx32 + 1 * S, 1.f);
    k_prop32<<<S / 256, 256, 0, stream>>>(rowp, ep, tx32 + 1 * S, tx32,         tx32 + 2 * S, 2.f);
    k_prop32<<<S / 256, 256, 0, stream>>>(rowp, ep, tx32 + 2 * S, tx32 + 1 * S, tx32 + 3 * S, 2.f);
    k_prop32<<<S / 256, 256, 0, stream>>>(rowp, ep, tx32 + 3 * S, tx32 + 2 * S, tx32 + 4 * S, 2.f);
    k_comb32<<<S / 256, 256, 0, stream>>>(tx32, W3, b3, h_a, 0);

    // ---- readout ----
    k_initout<<<5, 64, 0, stream>>>(bl, out);
    k_readout<<<NG * 16, 256, 0, stream>>>(h_a, Wl, out);
}

// Round 2
// 1083.439 us; speedup vs baseline: 1.2524x; 1.2524x over previous
//
#include <hip/hip_runtime.h>
#include <hip/hip_fp16.h>

#define NN   65536      // total nodes
#define EE   2097152    // edges
#define HID  32
#define KCH  5
#define OUTS 33
#define NG   8
#define GSZ  262144     // INPUT_SIZE * HIDDEN per graph
#define WLP  36         // padded fp16 row length for Wl (72 B, 8B-aligned)

// ---------------- degree histograms ----------------
__global__ __launch_bounds__(256) void k_hist(const int* __restrict__ ei,
                                              int* __restrict__ deg,
                                              int* __restrict__ indeg) {
    int e = blockIdx.x * 256 + threadIdx.x;
    atomicAdd(&deg[ei[e]], 1);          // out-degree by src
    atomicAdd(&indeg[ei[EE + e]], 1);   // in-degree by dst for CSR build
}

__global__ __launch_bounds__(256) void k_dinv(const int* __restrict__ deg,
                                              float* __restrict__ dinv) {
    int i = blockIdx.x * 256 + threadIdx.x;
    int d = deg[i];
    dinv[i] = d > 0 ? 1.0f / sqrtf((float)d) : 0.0f;
}

// ---------------- hierarchical exclusive scan over 65536 ints ----------------
// scan1: 64 blocks x 1024; block-local exclusive scan + block sums
__global__ __launch_bounds__(1024) void k_scan1(const int* __restrict__ indeg,
                                                int* __restrict__ excl,
                                                int* __restrict__ bsum) {
    __shared__ int wsum[16];
    int tid = threadIdx.x;
    int gid = blockIdx.x * 1024 + tid;
    int lane = tid & 63, w = tid >> 6;
    int v = indeg[gid];
    int s = v;
    #pragma unroll
    for (int off = 1; off < 64; off <<= 1) {
        int t = __shfl_up(s, off, 64);
        if (lane >= off) s += t;
    }
    if (lane == 63) wsum[w] = s;
    __syncthreads();
    if (w == 0) {
        int x = (lane < 16) ? wsum[lane] : 0;
        #pragma unroll
        for (int off = 1; off < 16; off <<= 1) {
            int t = __shfl_up(x, off, 64);
            if (lane >= off) x += t;
        }
        if (lane < 16) wsum[lane] = x;   // inclusive wave sums
    }
    __syncthreads();
    int base = (w > 0) ? wsum[w - 1] : 0;
    excl[gid] = base + s - v;            // block-local exclusive
    if (tid == 1023) bsum[blockIdx.x] = base + s;
}

// scan2: one wave scans 64 block sums -> exclusive bases (in place)
__global__ void k_scan2(int* __restrict__ bsum) {
    int lane = threadIdx.x;
    int v = bsum[lane];
    int s = v;
    #pragma unroll
    for (int off = 1; off < 64; off <<= 1) {
        int t = __shfl_up(s, off, 64);
        if (lane >= off) s += t;
    }
    bsum[lane] = s - v;
}

// scan3: add block base, emit row_ptr + cursor
__global__ __launch_bounds__(1024) void k_scan3(const int* __restrict__ excl,
                                                const int* __restrict__ bsum,
                                                int* __restrict__ rowp,
                                                int* __restrict__ cursor) {
    int gid = blockIdx.x * 1024 + threadIdx.x;
    int v = excl[gid] + bsum[blockIdx.x];
    rowp[gid] = v;
    cursor[gid] = v;
    if (blockIdx.x == 0 && threadIdx.x == 0) rowp[NN] = EE;
}

// ---------------- scatter edges into CSR, pack (src:16 | norm_fp16:16) ------
__global__ __launch_bounds__(256) void k_scatter(const int* __restrict__ ei,
                                                 const float* __restrict__ dinv,
                                                 int* __restrict__ cursor,
                                                 unsigned* __restrict__ ep) {
    int e = blockIdx.x * 256 + threadIdx.x;
    int s = ei[e], d = ei[EE + e];
    float nr = -(dinv[s] * dinv[d]);
    unsigned pk = (unsigned)s |
                  ((unsigned)__half_as_ushort(__float2half(nr)) << 16);
    int pos = atomicAdd(&cursor[d], 1);
    ep[pos] = pk;
}

// ---------------- width-1 propagation (layer 1, fp32) ----------------
__global__ __launch_bounds__(256) void k_prop1(const int* __restrict__ rowp,
                                               const unsigned* __restrict__ ep,
                                               const float* __restrict__ tin,
                                               const float* __restrict__ prev,
                                               float* __restrict__ tout,
                                               float alpha) {
    int n = blockIdx.x * 256 + threadIdx.x;
    int e0 = rowp[n], e1 = rowp[n + 1];
    float a0 = 0.f, a1 = 0.f;
    int e = e0;
    for (; e + 1 < e1; e += 2) {
        unsigned p0 = ep[e], p1 = ep[e + 1];
        a0 += __half2float(__ushort_as_half((unsigned short)(p0 >> 16))) * tin[p0 & 0xFFFF];
        a1 += __half2float(__ushort_as_half((unsigned short)(p1 >> 16))) * tin[p1 & 0xFFFF];
    }
    if (e < e1) {
        unsigned p = ep[e];
        a0 += __half2float(__ushort_as_half((unsigned short)(p >> 16))) * tin[p & 0xFFFF];
    }
    float r = alpha * (a0 + a1);
    if (prev) r -= prev[n];
    tout[n] = r;
}

// ---------------- width-32 fp16 propagation: 32 lanes/node, lane=feature ----
__global__ __launch_bounds__(256) void k_prop32(const int* __restrict__ rowp,
                                                const unsigned* __restrict__ ep,
                                                const __half* __restrict__ tin,
                                                const __half* __restrict__ prev,
                                                __half* __restrict__ tout,
                                                float alpha) {
    int idx = blockIdx.x * 256 + threadIdx.x;
    int n = idx >> 5, j = idx & 31;
    int e0 = rowp[n], e1 = rowp[n + 1];
    float a0 = 0.f, a1 = 0.f;
    int e = e0;
    for (; e + 1 < e1; e += 2) {
        unsigned p0 = ep[e], p1 = ep[e + 1];
        a0 += __half2float(__ushort_as_half((unsigned short)(p0 >> 16))) *
              __half2float(tin[((p0 & 0xFFFF) << 5) + j]);
        a1 += __half2float(__ushort_as_half((unsigned short)(p1 >> 16))) *
              __half2float(tin[((p1 & 0xFFFF) << 5) + j]);
    }
    if (e < e1) {
        unsigned p = ep[e];
        a0 += __half2float(__ushort_as_half((unsigned short)(p >> 16))) *
              __half2float(tin[((p & 0xFFFF) << 5) + j]);
    }
    float r = alpha * (a0 + a1);
    if (prev) r -= __half2float(prev[idx]);
    tout[idx] = __float2half(r);
}

// ---------------- layer-1 combine: h = relu(x*W[0] + sum_k tx_k*W[k] + b) ---
__global__ __launch_bounds__(256) void k_comb1(const float* __restrict__ x,
                                               const float* __restrict__ txr,
                                               const float* __restrict__ W,
                                               const float* __restrict__ b,
                                               __half* __restrict__ hout) {
    int idx = blockIdx.x * 256 + threadIdx.x;
    int n = idx >> 5, j = idx & 31;
    float acc = b[j] + x[n] * W[j];
#pragma unroll
    for (int k = 1; k < KCH; ++k)
        acc += txr[(k - 1) * NN + n] * W[k * HID + j];
    hout[idx] = __float2half(fmaxf(acc, 0.f));
}

// ---------------- 32-wide combine (may write in place into tx slot 0) -------
__global__ __launch_bounds__(256) void k_comb32(const __half* tx,
                                                const float* __restrict__ W,
                                                const float* __restrict__ b,
                                                __half* hout,
                                                int relu) {
    __shared__ float Ws[KCH * HID * HID];
    int tid = threadIdx.x;
    for (int t = tid; t < KCH * HID * HID; t += 256) Ws[t] = W[t];
    __syncthreads();
    int idx = blockIdx.x * 256 + tid;
    int n = idx >> 5, j = idx & 31;
    int lane = tid & 63;
    int base_lane = lane & 32;
    float acc = b[j];
#pragma unroll
    for (int k = 0; k < KCH; ++k) {
        float vk = __half2float(tx[(size_t)k * NN * HID + (n << 5) + j]);
#pragma unroll
        for (int i = 0; i < HID; ++i) {
            float a = __shfl(vk, base_lane + i, 64);
            acc += a * Ws[(k * HID + i) * HID + j];
        }
    }
    acc = relu ? fmaxf(acc, 0.f) : acc;
    hout[idx] = __float2half(acc);
}

// ---------------- Wl fp32 -> fp16 padded rows ----------------
__global__ __launch_bounds__(256) void k_cvt(const float* __restrict__ Wl,
                                             __half* __restrict__ Wlh) {
    int m = blockIdx.x * 256 + threadIdx.x;     // 262144 rows
    const float* src = Wl + (size_t)m * OUTS;
    __half* dst = Wlh + (size_t)m * WLP;
#pragma unroll
    for (int o = 0; o < OUTS; ++o) dst[o] = __float2half(src[o]);
    dst[33] = __float2half(0.f);
    dst[34] = __float2half(0.f);
    dst[35] = __float2half(0.f);
}

// ---------------- readout ----------------
__global__ void k_initout(const float* __restrict__ bl, float* __restrict__ out) {
    int i = blockIdx.x * 64 + threadIdx.x;
    if (i < NG * OUTS) out[i] = bl[i % OUTS];
}

__global__ __launch_bounds__(256) void k_readout(const __half* __restrict__ h,
                                                 const __half* __restrict__ Wlh,
                                                 float* __restrict__ out) {
    int gp = blockIdx.x >> 7;        // graph pair 0..3
    int mc = blockIdx.x & 127;       // m-chunk 0..127 (2048 rows each)
    int tid = threadIdx.x;
    int g0 = gp * 2, g1 = g0 + 1;
    float acc0[OUTS], acc1[OUTS];
#pragma unroll
    for (int o = 0; o < OUTS; ++o) { acc0[o] = 0.f; acc1[o] = 0.f; }
    const __half* h0 = h + (size_t)g0 * GSZ;
    const __half* h1 = h + (size_t)g1 * GSZ;
    for (int it = 0; it < 8; ++it) {
        int m = mc * 2048 + it * 256 + tid;
        float hv0 = __half2float(h0[m]);
        float hv1 = __half2float(h1[m]);
        const __half2* rp = (const __half2*)(Wlh + (size_t)m * WLP);
        __half2 rw[17];
#pragma unroll
        for (int q = 0; q < 17; ++q) rw[q] = rp[q];
#pragma unroll
        for (int q = 0; q < 16; ++q) {
            float2 f = __half22float2(rw[q]);
            acc0[2 * q]     += hv0 * f.x;  acc1[2 * q]     += hv1 * f.x;
            acc0[2 * q + 1] += hv0 * f.y;  acc1[2 * q + 1] += hv1 * f.y;
        }
        float lw = __half2float(__low2half(rw[16]));
        acc0[32] += hv0 * lw;  acc1[32] += hv1 * lw;
    }
    __shared__ float red[4][2 * OUTS];
    int lane = tid & 63, w = tid >> 6;
#pragma unroll
    for (int o = 0; o < OUTS; ++o) {
        float v0 = acc0[o], v1 = acc1[o];
        for (int off = 32; off > 0; off >>= 1) {
            v0 += __shfl_down(v0, off, 64);
            v1 += __shfl_down(v1, off, 64);
        }
        if (lane == 0) { red[w][o] = v0; red[w][OUTS + o] = v1; }
    }
    __syncthreads();
    if (tid < 2 * OUTS) {
        float s = red[0][tid] + red[1][tid] + red[2][tid] + red[3][tid];
        int g = (tid < OUTS) ? g0 : g1;
        int o = (tid < OUTS) ? tid : tid - OUTS;
        atomicAdd(&out[g * OUTS + o], s);
    }
}

extern "C" void kernel_launch(void* const* d_in, const int* in_sizes, int n_in,
                              void* d_out, int out_size, void* d_ws, size_t ws_size,
                              hipStream_t stream) {
    const float* x  = (const float*)d_in[0];
    const int*   ei = (const int*)d_in[1];
    const float* W1 = (const float*)d_in[3];
    const float* b1 = (const float*)d_in[4];
    const float* W2 = (const float*)d_in[5];
    const float* b2 = (const float*)d_in[6];
    const float* W3 = (const float*)d_in[7];
    const float* b3 = (const float*)d_in[8];
    const float* Wl = (const float*)d_in[9];
    const float* bl = (const float*)d_in[10];
    float* out = (float*)d_out;

    char* ws = (char*)d_ws;
    size_t off = 0;
    auto alloc = [&](size_t bytes) -> void* {
        void* p = ws + off;
        off += (bytes + 255) & ~(size_t)255;
        return p;
    };
    int*      deg    = (int*)alloc((size_t)NN * 4);
    int*      indeg  = (int*)alloc((size_t)NN * 4);
    int*      rowp   = (int*)alloc((size_t)(NN + 1) * 4);
    int*      cursor = (int*)alloc((size_t)NN * 4);
    int*      excl   = (int*)alloc((size_t)NN * 4);
    int*      bsum   = (int*)alloc(64 * 4);
    float*    dinv   = (float*)alloc((size_t)NN * 4);
    unsigned* ep     = (unsigned*)alloc((size_t)EE * 4);
    float*    txw1   = (float*)alloc((size_t)4 * NN * 4);        // T1..T4, width 1
    __half*   tx32   = (__half*)alloc((size_t)KCH * NN * HID * 2);
    __half*   hfin   = (__half*)alloc((size_t)NN * HID * 2);
    __half*   Wlh    = (__half*)alloc((size_t)GSZ * WLP * 2);

    hipMemsetAsync(deg,   0, (size_t)NN * 4, stream);
    hipMemsetAsync(indeg, 0, (size_t)NN * 4, stream);
    k_hist<<<EE / 256, 256, 0, stream>>>(ei, deg, indeg);
    k_dinv<<<NN / 256, 256, 0, stream>>>(deg, dinv);
    k_scan1<<<64, 1024, 0, stream>>>(indeg, excl, bsum);
    k_scan2<<<1, 64, 0, stream>>>(bsum);
    k_scan3<<<64, 1024, 0, stream>>>(excl, bsum, rowp, cursor);
    k_scatter<<<EE / 256, 256, 0, stream>>>(ei, dinv, cursor, ep);
    k_cvt<<<GSZ / 256, 256, 0, stream>>>(Wl, Wlh);

    // ---- layer 1 (width-1, fp32 recurrence; plane k stored at txw1+(k-1)N) ----
    float *t1 = txw1, *t2 = txw1 + NN, *t3 = txw1 + 2 * NN, *t4 = txw1 + 3 * NN;
    k_prop1<<<NN / 256, 256, 0, stream>>>(rowp, ep, x,  nullptr, t1, 1.f);
    k_prop1<<<NN / 256, 256, 0, stream>>>(rowp, ep, t1, x,       t2, 2.f);
    k_prop1<<<NN / 256, 256, 0, stream>>>(rowp, ep, t2, t1,      t3, 2.f);
    k_prop1<<<NN / 256, 256, 0, stream>>>(rowp, ep, t3, t2,      t4, 2.f);
    k_comb1<<<(NN * HID) / 256, 256, 0, stream>>>(x, txw1, W1, b1, tx32);  // -> slot 0

    const size_t S = (size_t)NN * HID;
    // ---- layer 2 ----
    k_prop32<<<S / 256, 256, 0, stream>>>(rowp, ep, tx32,         nullptr,      tx32 + 1 * S, 1.f);
    k_prop32<<<S / 256, 256, 0, stream>>>(rowp, ep, tx32 + 1 * S, tx32,         tx32 + 2 * S, 2.f);
    k_prop32<<<S / 256, 256, 0, stream>>>(rowp, ep, tx32 + 2 * S, tx32 + 1 * S, tx32 + 3 * S, 2.f);
    k_prop32<<<S / 256, 256, 0, stream>>>(rowp, ep, tx32 + 3 * S, tx32 + 2 * S, tx32 + 4 * S, 2.f);
    k_comb32<<<S / 256, 256, 0, stream>>>(tx32, W2, b2, tx32, 1);            // in-place slot 0

    // ---- layer 3 (no relu) ----
    k_prop32<<<S / 256, 256, 0, stream>>>(rowp, ep, tx32,         nullptr,      tx32 + 1 * S, 1.f);
    k_prop32<<<S / 256, 256, 0, stream>>>(rowp, ep, tx32 + 1 * S, tx32,         tx32 + 2 * S, 2.f);
    k_prop32<<<S / 256, 256, 0, stream>>>(rowp, ep, tx32 + 2 * S, tx32 + 1 * S, tx32 + 3 * S, 2.f);
    k_prop32<<<S / 256, 256, 0, stream>>>(rowp, ep, tx32 + 3 * S, tx32 + 2 * S, tx32 + 4 * S, 2.f);
    k_comb32<<<S / 256, 256, 0, stream>>>(tx32, W3, b3, hfin, 0);

    // ---- readout ----
    k_initout<<<5, 64, 0, stream>>>(bl, out);
    k_readout<<<512, 256, 0, stream>>>(hfin, Wlh, out);
}

// Round 3
// 793.423 us; speedup vs baseline: 1.7102x; 1.3655x over previous
//
#include <hip/hip_runtime.h>
#include <hip/hip_fp16.h>

#define NN     65536    // total nodes
#define EE     2097152  // edges
#define HID    32
#define KCH    5
#define OUTS   33
#define NG     8
#define GSZ    262144   // INPUT_SIZE * HIDDEN per graph
#define WLP    36       // padded fp16 row length for Wl
#define SLICES 64       // edge slices for histogram
#define RSIZE  32768    // counters per range (2 ranges cover 64K nodes)

// ---------------- LDS-privatized histogram (no global atomics) --------------
// grid 256: b = {arr:1, range:1, slice:6}; partial counts stored as uchar.
__global__ __launch_bounds__(1024) void k_hist(const int* __restrict__ ei,
                                               unsigned char* __restrict__ pdeg,
                                               unsigned char* __restrict__ pind) {
    __shared__ unsigned cnt[RSIZE];
    int b = blockIdx.x;
    int arr = b >> 7, r = (b >> 6) & 1, s = b & 63;
    const int* keys = ei + (arr ? EE : 0) + s * (EE / SLICES);
    unsigned char* pout = (arr ? pind : pdeg) + (size_t)(r * SLICES + s) * RSIZE;
    int tid = threadIdx.x;
    for (int i = tid; i < RSIZE; i += 1024) cnt[i] = 0;
    __syncthreads();
    int lo = r * RSIZE, hi = lo + RSIZE;
    for (int i = tid; i < EE / SLICES; i += 1024) {
        int k = keys[i];
        if (k >= lo && k < hi) atomicAdd(&cnt[k - lo], 1u);
    }
    __syncthreads();
    unsigned* pout4 = (unsigned*)pout;
    for (int i = tid; i < RSIZE / 4; i += 1024) {
        unsigned c0 = cnt[4 * i], c1 = cnt[4 * i + 1];
        unsigned c2 = cnt[4 * i + 2], c3 = cnt[4 * i + 3];
        pout4[i] = c0 | (c1 << 8) | (c2 << 16) | (c3 << 24);
    }
}

// reduce partials -> dinv (from deg) and indeg
__global__ __launch_bounds__(256) void k_hreduce(const unsigned char* __restrict__ pdeg,
                                                 const unsigned char* __restrict__ pind,
                                                 float* __restrict__ dinv,
                                                 int* __restrict__ indeg) {
    int t = blockIdx.x * 256 + threadIdx.x;   // 2 * 16384 threads
    int arr = t >> 14;
    int q = t & 16383;                        // uint index over 64K counters
    int r = q >> 13;                          // 8192 uints per range
    int ql = q & 8191;
    const unsigned char* P = arr ? pind : pdeg;
    const unsigned* base = (const unsigned*)(P + (size_t)r * SLICES * RSIZE) + ql;
    unsigned s0 = 0, s1 = 0, s2 = 0, s3 = 0;
#pragma unroll 8
    for (int s = 0; s < SLICES; ++s) {
        unsigned v = base[s * (RSIZE / 4)];
        s0 += v & 0xFF; s1 += (v >> 8) & 0xFF; s2 += (v >> 16) & 0xFF; s3 += v >> 24;
    }
    int c = (r << 15) + 4 * ql;
    if (arr == 0) {
        dinv[c]     = s0 ? 1.0f / sqrtf((float)s0) : 0.0f;
        dinv[c + 1] = s1 ? 1.0f / sqrtf((float)s1) : 0.0f;
        dinv[c + 2] = s2 ? 1.0f / sqrtf((float)s2) : 0.0f;
        dinv[c + 3] = s3 ? 1.0f / sqrtf((float)s3) : 0.0f;
    } else {
        indeg[c] = s0; indeg[c + 1] = s1; indeg[c + 2] = s2; indeg[c + 3] = s3;
    }
}

// ---------------- hierarchical exclusive scan over 65536 ints ----------------
__global__ __launch_bounds__(1024) void k_scan1(const int* __restrict__ indeg,
                                                int* __restrict__ excl,
                                                int* __restrict__ bsum) {
    __shared__ int wsum[16];
    int tid = threadIdx.x;
    int gid = blockIdx.x * 1024 + tid;
    int lane = tid & 63, w = tid >> 6;
    int v = indeg[gid];
    int s = v;
    #pragma unroll
    for (int off = 1; off < 64; off <<= 1) {
        int t = __shfl_up(s, off, 64);
        if (lane >= off) s += t;
    }
    if (lane == 63) wsum[w] = s;
    __syncthreads();
    if (w == 0) {
        int x = (lane < 16) ? wsum[lane] : 0;
        #pragma unroll
        for (int off = 1; off < 16; off <<= 1) {
            int t = __shfl_up(x, off, 64);
            if (lane >= off) x += t;
        }
        if (lane < 16) wsum[lane] = x;
    }
    __syncthreads();
    int base = (w > 0) ? wsum[w - 1] : 0;
    excl[gid] = base + s - v;
    if (tid == 1023) bsum[blockIdx.x] = base + s;
}

__global__ void k_scan2(int* __restrict__ bsum) {
    int lane = threadIdx.x;
    int v = bsum[lane];
    int s = v;
    #pragma unroll
    for (int off = 1; off < 64; off <<= 1) {
        int t = __shfl_up(s, off, 64);
        if (lane >= off) s += t;
    }
    bsum[lane] = s - v;
}

__global__ __launch_bounds__(1024) void k_scan3(const int* __restrict__ excl,
                                                const int* __restrict__ bsum,
                                                int* __restrict__ rowp,
                                                int* __restrict__ cursor) {
    int gid = blockIdx.x * 1024 + threadIdx.x;
    int v = excl[gid] + bsum[blockIdx.x];
    rowp[gid] = v;
    cursor[gid] = v;
    if (blockIdx.x == 0 && threadIdx.x == 0) rowp[NN] = EE;
}

// ---------------- scatter edges into CSR, pack (src:16 | norm_fp16:16) ------
__global__ __launch_bounds__(256) void k_scatter(const int* __restrict__ ei,
                                                 const float* __restrict__ dinv,
                                                 int* __restrict__ cursor,
                                                 unsigned* __restrict__ ep) {
    int e = blockIdx.x * 256 + threadIdx.x;
    int s = ei[e], d = ei[EE + e];
    float nr = -(dinv[s] * dinv[d]);
    unsigned pk = (unsigned)s |
                  ((unsigned)__half_as_ushort(__float2half(nr)) << 16);
    int pos = atomicAdd(&cursor[d], 1);
    ep[pos] = pk;
}

// ---------------- width-1 propagation (layer 1, fp32) ----------------
__global__ __launch_bounds__(256) void k_prop1(const int* __restrict__ rowp,
                                               const unsigned* __restrict__ ep,
                                               const float* __restrict__ tin,
                                               const float* __restrict__ prev,
                                               float* __restrict__ tout,
                                               float alpha) {
    int n = blockIdx.x * 256 + threadIdx.x;
    int e0 = rowp[n], e1 = rowp[n + 1];
    float a0 = 0.f, a1 = 0.f;
    int e = e0;
    for (; e + 1 < e1; e += 2) {
        unsigned p0 = ep[e], p1 = ep[e + 1];
        a0 += __half2float(__ushort_as_half((unsigned short)(p0 >> 16))) * tin[p0 & 0xFFFF];
        a1 += __half2float(__ushort_as_half((unsigned short)(p1 >> 16))) * tin[p1 & 0xFFFF];
    }
    if (e < e1) {
        unsigned p = ep[e];
        a0 += __half2float(__ushort_as_half((unsigned short)(p >> 16))) * tin[p & 0xFFFF];
    }
    float r = alpha * (a0 + a1);
    if (prev) r -= prev[n];
    tout[n] = r;
}

// ------- width-32 fp16 propagation: 16 lanes/node, lane = feature pair ------
__global__ __launch_bounds__(256) void k_prop32(const int* __restrict__ rowp,
                                                const unsigned* __restrict__ ep,
                                                const __half* __restrict__ tin,
                                                const __half* __restrict__ prev,
                                                __half* __restrict__ tout,
                                                float alpha) {
    int idx = blockIdx.x * 256 + threadIdx.x;
    int n = idx >> 4, jp = (idx & 15) << 1;
    int e0 = rowp[n], e1 = rowp[n + 1];
    float ax0 = 0.f, ay0 = 0.f, ax1 = 0.f, ay1 = 0.f;
    int e = e0;
    for (; e + 1 < e1; e += 2) {
        unsigned p0 = ep[e], p1 = ep[e + 1];
        __half2 v0 = *(const __half2*)(tin + ((p0 & 0xFFFFu) << 5) + jp);
        __half2 v1 = *(const __half2*)(tin + ((p1 & 0xFFFFu) << 5) + jp);
        float w0 = __half2float(__ushort_as_half((unsigned short)(p0 >> 16)));
        float w1 = __half2float(__ushort_as_half((unsigned short)(p1 >> 16)));
        float2 f0 = __half22float2(v0), f1 = __half22float2(v1);
        ax0 += w0 * f0.x; ay0 += w0 * f0.y;
        ax1 += w1 * f1.x; ay1 += w1 * f1.y;
    }
    if (e < e1) {
        unsigned p = ep[e];
        __half2 v = *(const __half2*)(tin + ((p & 0xFFFFu) << 5) + jp);
        float w = __half2float(__ushort_as_half((unsigned short)(p >> 16)));
        float2 f = __half22float2(v);
        ax0 += w * f.x; ay0 += w * f.y;
    }
    float rx = alpha * (ax0 + ax1), ry = alpha * (ay0 + ay1);
    int o = (n << 5) + jp;
    if (prev) {
        float2 pv = __half22float2(*(const __half2*)(prev + o));
        rx -= pv.x; ry -= pv.y;
    }
    *(__half2*)(tout + o) = __floats2half2_rn(rx, ry);
}

// ---------------- layer-1 combine: h = relu(x*W[0] + sum_k tx_k*W[k] + b) ---
__global__ __launch_bounds__(256) void k_comb1(const float* __restrict__ x,
                                               const float* __restrict__ txr,
                                               const float* __restrict__ W,
                                               const float* __restrict__ b,
                                               __half* __restrict__ hout) {
    int idx = blockIdx.x * 256 + threadIdx.x;
    int n = idx >> 5, j = idx & 31;
    float acc = b[j] + x[n] * W[j];
#pragma unroll
    for (int k = 1; k < KCH; ++k)
        acc += txr[(k - 1) * NN + n] * W[k * HID + j];
    hout[idx] = __float2half(fmaxf(acc, 0.f));
}

// ---------------- 32-wide combine (may write in place into tx slot 0) -------
__global__ __launch_bounds__(256) void k_comb32(const __half* tx,
                                                const float* __restrict__ W,
                                                const float* __restrict__ b,
                                                __half* hout,
                                                int relu) {
    __shared__ float Ws[KCH * HID * HID];
    int tid = threadIdx.x;
    for (int t = tid; t < KCH * HID * HID; t += 256) Ws[t] = W[t];
    __syncthreads();
    int idx = blockIdx.x * 256 + tid;
    int n = idx >> 5, j = idx & 31;
    int lane = tid & 63;
    int base_lane = lane & 32;
    float acc = b[j];
#pragma unroll
    for (int k = 0; k < KCH; ++k) {
        float vk = __half2float(tx[(size_t)k * NN * HID + (n << 5) + j]);
#pragma unroll
        for (int i = 0; i < HID; ++i) {
            float a = __shfl(vk, base_lane + i, 64);
            acc += a * Ws[(k * HID + i) * HID + j];
        }
    }
    acc = relu ? fmaxf(acc, 0.f) : acc;
    hout[idx] = __float2half(acc);
}

// ---------------- Wl fp32 -> fp16 padded rows ----------------
__global__ __launch_bounds__(256) void k_cvt(const float* __restrict__ Wl,
                                             __half* __restrict__ Wlh) {
    int m = blockIdx.x * 256 + threadIdx.x;
    const float* src = Wl + (size_t)m * OUTS;
    __half* dst = Wlh + (size_t)m * WLP;
#pragma unroll
    for (int o = 0; o < OUTS; ++o) dst[o] = __float2half(src[o]);
    dst[33] = __float2half(0.f);
    dst[34] = __float2half(0.f);
    dst[35] = __float2half(0.f);
}

// ---------------- readout ----------------
__global__ void k_initout(const float* __restrict__ bl, float* __restrict__ out) {
    int i = blockIdx.x * 64 + threadIdx.x;
    if (i < NG * OUTS) out[i] = bl[i % OUTS];
}

__global__ __launch_bounds__(256) void k_readout(const __half* __restrict__ h,
                                                 const __half* __restrict__ Wlh,
                                                 float* __restrict__ out) {
    int gp = blockIdx.x >> 7;
    int mc = blockIdx.x & 127;
    int tid = threadIdx.x;
    int g0 = gp * 2, g1 = g0 + 1;
    float acc0[OUTS], acc1[OUTS];
#pragma unroll
    for (int o = 0; o < OUTS; ++o) { acc0[o] = 0.f; acc1[o] = 0.f; }
    const __half* h0 = h + (size_t)g0 * GSZ;
    const __half* h1 = h + (size_t)g1 * GSZ;
    for (int it = 0; it < 8; ++it) {
        int m = mc * 2048 + it * 256 + tid;
        float hv0 = __half2float(h0[m]);
        float hv1 = __half2float(h1[m]);
        const __half2* rp = (const __half2*)(Wlh + (size_t)m * WLP);
        __half2 rw[17];
#pragma unroll
        for (int q = 0; q < 17; ++q) rw[q] = rp[q];
#pragma unroll
        for (int q = 0; q < 16; ++q) {
            float2 f = __half22float2(rw[q]);
            acc0[2 * q]     += hv0 * f.x;  acc1[2 * q]     += hv1 * f.x;
            acc0[2 * q + 1] += hv0 * f.y;  acc1[2 * q + 1] += hv1 * f.y;
        }
        float lw = __half2float(__low2half(rw[16]));
        acc0[32] += hv0 * lw;  acc1[32] += hv1 * lw;
    }
    __shared__ float red[4][2 * OUTS];
    int lane = tid & 63, w = tid >> 6;
#pragma unroll
    for (int o = 0; o < OUTS; ++o) {
        float v0 = acc0[o], v1 = acc1[o];
        for (int off = 32; off > 0; off >>= 1) {
            v0 += __shfl_down(v0, off, 64);
            v1 += __shfl_down(v1, off, 64);
        }
        if (lane == 0) { red[w][o] = v0; red[w][OUTS + o] = v1; }
    }
    __syncthreads();
    if (tid < 2 * OUTS) {
        float s = red[0][tid] + red[1][tid] + red[2][tid] + red[3][tid];
        int g = (tid < OUTS) ? g0 : g1;
        int o = (tid < OUTS) ? tid : tid - OUTS;
        atomicAdd(&out[g * OUTS + o], s);
    }
}

extern "C" void kernel_launch(void* const* d_in, const int* in_sizes, int n_in,
                              void* d_out, int out_size, void* d_ws, size_t ws_size,
                              hipStream_t stream) {
    const float* x  = (const float*)d_in[0];
    const int*   ei = (const int*)d_in[1];
    const float* W1 = (const float*)d_in[3];
    const float* b1 = (const float*)d_in[4];
    const float* W2 = (const float*)d_in[5];
    const float* b2 = (const float*)d_in[6];
    const float* W3 = (const float*)d_in[7];
    const float* b3 = (const float*)d_in[8];
    const float* Wl = (const float*)d_in[9];
    const float* bl = (const float*)d_in[10];
    float* out = (float*)d_out;

    char* ws = (char*)d_ws;
    size_t off = 0;
    auto alloc = [&](size_t bytes) -> void* {
        void* p = ws + off;
        off += (bytes + 255) & ~(size_t)255;
        return p;
    };
    unsigned char* pdeg = (unsigned char*)alloc((size_t)2 * SLICES * RSIZE);
    unsigned char* pind = (unsigned char*)alloc((size_t)2 * SLICES * RSIZE);
    int*      indeg  = (int*)alloc((size_t)NN * 4);
    int*      rowp   = (int*)alloc((size_t)(NN + 1) * 4);
    int*      cursor = (int*)alloc((size_t)NN * 4);
    int*      excl   = (int*)alloc((size_t)NN * 4);
    int*      bsum   = (int*)alloc(64 * 4);
    float*    dinv   = (float*)alloc((size_t)NN * 4);
    unsigned* ep     = (unsigned*)alloc((size_t)EE * 4);
    float*    txw1   = (float*)alloc((size_t)4 * NN * 4);
    __half*   tx32   = (__half*)alloc((size_t)KCH * NN * HID * 2);
    __half*   hfin   = (__half*)alloc((size_t)NN * HID * 2);
    __half*   Wlh    = (__half*)alloc((size_t)GSZ * WLP * 2);

    k_hist<<<256, 1024, 0, stream>>>(ei, pdeg, pind);
    k_hreduce<<<128, 256, 0, stream>>>(pdeg, pind, dinv, indeg);
    k_scan1<<<64, 1024, 0, stream>>>(indeg, excl, bsum);
    k_scan2<<<1, 64, 0, stream>>>(bsum);
    k_scan3<<<64, 1024, 0, stream>>>(excl, bsum, rowp, cursor);
    k_scatter<<<EE / 256, 256, 0, stream>>>(ei, dinv, cursor, ep);
    k_cvt<<<GSZ / 256, 256, 0, stream>>>(Wl, Wlh);

    // ---- layer 1 (width-1, fp32 recurrence) ----
    float *t1 = txw1, *t2 = txw1 + NN, *t3 = txw1 + 2 * NN, *t4 = txw1 + 3 * NN;
    k_prop1<<<NN / 256, 256, 0, stream>>>(rowp, ep, x,  nullptr, t1, 1.f);
    k_prop1<<<NN / 256, 256, 0, stream>>>(rowp, ep, t1, x,       t2, 2.f);
    k_prop1<<<NN / 256, 256, 0, stream>>>(rowp, ep, t2, t1,      t3, 2.f);
    k_prop1<<<NN / 256, 256, 0, stream>>>(rowp, ep, t3, t2,      t4, 2.f);
    k_comb1<<<(NN * HID) / 256, 256, 0, stream>>>(x, txw1, W1, b1, tx32);

    const size_t S = (size_t)NN * HID;
    const int PG = (NN * 16) / 256;   // 4096 blocks for 16-lane prop
    // ---- layer 2 ----
    k_prop32<<<PG, 256, 0, stream>>>(rowp, ep, tx32,         nullptr,      tx32 + 1 * S, 1.f);
    k_prop32<<<PG, 256, 0, stream>>>(rowp, ep, tx32 + 1 * S, tx32,         tx32 + 2 * S, 2.f);
    k_prop32<<<PG, 256, 0, stream>>>(rowp, ep, tx32 + 2 * S, tx32 + 1 * S, tx32 + 3 * S, 2.f);
    k_prop32<<<PG, 256, 0, stream>>>(rowp, ep, tx32 + 3 * S, tx32 + 2 * S, tx32 + 4 * S, 2.f);
    k_comb32<<<S / 256, 256, 0, stream>>>(tx32, W2, b2, tx32, 1);

    // ---- layer 3 (no relu) ----
    k_prop32<<<PG, 256, 0, stream>>>(rowp, ep, tx32,         nullptr,      tx32 + 1 * S, 1.f);
    k_prop32<<<PG, 256, 0, stream>>>(rowp, ep, tx32 + 1 * S, tx32,         tx32 + 2 * S, 2.f);
    k_prop32<<<PG, 256, 0, stream>>>(rowp, ep, tx32 + 2 * S, tx32 + 1 * S, tx32 + 3 * S, 2.f);
    k_prop32<<<PG, 256, 0, stream>>>(rowp, ep, tx32 + 3 * S, tx32 + 2 * S, tx32 + 4 * S, 2.f);
    k_comb32<<<S / 256, 256, 0, stream>>>(tx32, W3, b3, hfin, 0);

    // ---- readout ----
    k_initout<<<5, 64, 0, stream>>>(bl, out);
    k_readout<<<512, 256, 0, stream>>>(hfin, Wlh, out);
}

// Round 4
// 636.516 us; speedup vs baseline: 2.1317x; 1.2465x over previous
//
#include <hip/hip_runtime.h>
#include <hip/hip_fp16.h>

#define NN     65536    // total nodes
#define EE     2097152  // edges
#define HID    32
#define KCH    5
#define OUTS   33
#define NG     8
#define GSZ    262144   // INPUT_SIZE * HIDDEN per graph
#define WLP    36       // padded fp16 row length for Wl
#define SLICES 64       // edge slices for src histogram
#define RSIZE  32768    // counters per range (2 ranges cover 64K nodes)
#define BSL    16384    // edges per bucketing slice (128 slices)
#define NBK    256      // coarse buckets (dst >> 8)
#define STG    9472     // LDS staging capacity in k_place (mean 8192, ~14 sigma)

// exclusive scan of sh[0..255] in place; whole block must call
__device__ __forceinline__ void exscan256(int tid, int* __restrict__ sh,
                                          int* __restrict__ wsc) {
    int v = 0, s = 0;
    if (tid < 256) {
        v = sh[tid];
        s = v;
        int lane = tid & 63;
        #pragma unroll
        for (int off = 1; off < 64; off <<= 1) {
            int t = __shfl_up(s, off, 64);
            if (lane >= off) s += t;
        }
        if (lane == 63) wsc[tid >> 6] = s;
    }
    __syncthreads();
    if (tid == 0) {
        int a = 0;
        #pragma unroll
        for (int i = 0; i < 4; ++i) { int t = wsc[i]; wsc[i] = a; a += t; }
    }
    __syncthreads();
    if (tid < 256) sh[tid] = s - v + wsc[tid >> 6];
    __syncthreads();
}

// ---------------- src out-degree histogram (LDS-privatized) -----------------
// grid 128: b = {range:1, slice:6}; partial counts stored as uchar
__global__ __launch_bounds__(1024) void k_hist(const int* __restrict__ ei,
                                               unsigned char* __restrict__ pdeg) {
    __shared__ unsigned cnt[RSIZE];
    int b = blockIdx.x;
    int r = (b >> 6) & 1, s = b & 63;
    const int* keys = ei + s * (EE / SLICES);
    unsigned char* pout = pdeg + (size_t)(r * SLICES + s) * RSIZE;
    int tid = threadIdx.x;
    for (int i = tid; i < RSIZE; i += 1024) cnt[i] = 0;
    __syncthreads();
    int lo = r * RSIZE, hi = lo + RSIZE;
    for (int i = tid; i < EE / SLICES; i += 1024) {
        int k = keys[i];
        if (k >= lo && k < hi) atomicAdd(&cnt[k - lo], 1u);
    }
    __syncthreads();
    unsigned* pout4 = (unsigned*)pout;
    for (int i = tid; i < RSIZE / 4; i += 1024) {
        unsigned c0 = cnt[4 * i], c1 = cnt[4 * i + 1];
        unsigned c2 = cnt[4 * i + 2], c3 = cnt[4 * i + 3];
        pout4[i] = c0 | (c1 << 8) | (c2 << 16) | (c3 << 24);
    }
}

// reduce partials -> dinv
__global__ __launch_bounds__(256) void k_hreduce(const unsigned char* __restrict__ pdeg,
                                                 float* __restrict__ dinv) {
    int t = blockIdx.x * 256 + threadIdx.x;   // 16384 threads
    int r = t >> 13, ql = t & 8191;
    const unsigned* base = (const unsigned*)(pdeg + (size_t)r * SLICES * RSIZE) + ql;
    unsigned s0 = 0, s1 = 0, s2 = 0, s3 = 0;
#pragma unroll 8
    for (int s = 0; s < SLICES; ++s) {
        unsigned v = base[s * (RSIZE / 4)];
        s0 += v & 0xFF; s1 += (v >> 8) & 0xFF; s2 += (v >> 16) & 0xFF; s3 += v >> 24;
    }
    int c = (r << 15) + 4 * ql;
    dinv[c]     = s0 ? 1.0f / sqrtf((float)s0) : 0.0f;
    dinv[c + 1] = s1 ? 1.0f / sqrtf((float)s1) : 0.0f;
    dinv[c + 2] = s2 ? 1.0f / sqrtf((float)s2) : 0.0f;
    dinv[c + 3] = s3 ? 1.0f / sqrtf((float)s3) : 0.0f;
}

// ---------------- per-(slice, bucket) dst counts ----------------------------
__global__ __launch_bounds__(1024) void k_bcnt(const int* __restrict__ ei,
                                               int* __restrict__ bcnt) {
    __shared__ int cnt[NBK];
    int s = blockIdx.x, tid = threadIdx.x;
    if (tid < NBK) cnt[tid] = 0;
    __syncthreads();
    const int* dsts = ei + EE + s * BSL;
    for (int i = tid; i < BSL; i += 1024)
        atomicAdd(&cnt[dsts[i] >> 8], 1);
    __syncthreads();
    if (tid < NBK) bcnt[s * NBK + tid] = cnt[tid];
}

// scan: bcnt[s][b] -> global output offsets (in place); bbase[b] = bucket start
__global__ __launch_bounds__(256) void k_bscan(int* __restrict__ bcnt,
                                               int* __restrict__ bbase) {
    __shared__ int tot[256];
    __shared__ int wsc[4];
    int b = threadIdx.x;
    int run = 0;
    for (int s = 0; s < 128; ++s) {
        int c = bcnt[s * NBK + b];
        bcnt[s * NBK + b] = run;
        run += c;
    }
    tot[b] = run;
    __syncthreads();
    exscan256(b, tot, wsc);
    bbase[b] = tot[b];
    if (b == 0) bbase[256] = EE;
    for (int s = 0; s < 128; ++s)
        bcnt[s * NBK + b] += tot[b];
}

// ---------------- coarse bucketing: LDS counting sort, coalesced flush ------
__global__ __launch_bounds__(1024) void k_bucket(const int* __restrict__ ei,
                                                 const int* __restrict__ boff,
                                                 unsigned* __restrict__ bkt) {
    __shared__ unsigned stage[BSL];
    __shared__ int cnt[NBK], cur[NBK], gbase[NBK];
    __shared__ int wsc[4];
    int s = blockIdx.x, tid = threadIdx.x;
    if (tid < NBK) cnt[tid] = 0;
    __syncthreads();
    const int* srcs = ei + s * BSL;
    const int* dsts = ei + EE + s * BSL;
    for (int i = tid; i < BSL; i += 1024)
        atomicAdd(&cnt[dsts[i] >> 8], 1);
    __syncthreads();
    if (tid < NBK) gbase[tid] = boff[s * NBK + tid];
    exscan256(tid, cnt, wsc);                 // cnt -> local starts
    if (tid < NBK) cur[tid] = cnt[tid];
    __syncthreads();
    for (int i = tid; i < BSL; i += 1024) {
        int d = dsts[i];
        int pos = atomicAdd(&cur[d >> 8], 1);
        stage[pos] = (unsigned)srcs[i] | ((unsigned)d << 16);   // src:16 | dst:16
    }
    __syncthreads();
    for (int j = tid; j < BSL; j += 1024) {
        unsigned rec = stage[j];
        int b = rec >> 24;                    // dst >> 8
        bkt[gbase[b] + (j - cnt[b])] = rec;   // coalesced runs
    }
}

// ---------------- fine placement: exact CSR, packed ep, rowp ----------------
__global__ __launch_bounds__(512) void k_place(const unsigned* __restrict__ bkt,
                                               const int* __restrict__ bbase,
                                               const float* __restrict__ dinv,
                                               unsigned* __restrict__ ep,
                                               int* __restrict__ rowp) {
    __shared__ unsigned stage[STG];
    __shared__ int hist[NBK], cur[NBK];
    __shared__ float dl[NBK];
    __shared__ int wsc[4];
    int b = blockIdx.x, tid = threadIdx.x;
    int base = bbase[b], cnt = bbase[b + 1] - base;
    if (tid < NBK) { hist[tid] = 0; dl[tid] = dinv[b * NBK + tid]; }
    __syncthreads();
    const unsigned* recs = bkt + base;
    for (int i = tid; i < cnt; i += 512)
        atomicAdd(&hist[(recs[i] >> 16) & 255], 1);
    __syncthreads();
    exscan256(tid, hist, wsc);
    if (tid < NBK) {
        cur[tid] = hist[tid];
        rowp[b * NBK + tid] = base + hist[tid];
    }
    if (b == 0 && tid == 0) rowp[NN] = EE;
    __syncthreads();
    for (int i = tid; i < cnt; i += 512) {
        unsigned rec = recs[i];
        int srcv = rec & 0xFFFF;
        int dlow = (rec >> 16) & 255;
        float nr = -(dinv[srcv] * dl[dlow]);
        unsigned pk = (unsigned)srcv |
                      ((unsigned)__half_as_ushort(__float2half(nr)) << 16);
        int pos = atomicAdd(&cur[dlow], 1);
        if (pos < STG) stage[pos] = pk; else ep[base + pos] = pk;
    }
    __syncthreads();
    int lim = cnt < STG ? cnt : STG;
    for (int j = tid; j < lim; j += 512)
        ep[base + j] = stage[j];              // coalesced
}

// ---------------- width-1 propagation (layer 1, fp32) ----------------
__global__ __launch_bounds__(256) void k_prop1(const int* __restrict__ rowp,
                                               const unsigned* __restrict__ ep,
                                               const float* __restrict__ tin,
                                               const float* __restrict__ prev,
                                               float* __restrict__ tout,
                                               float alpha) {
    int n = blockIdx.x * 256 + threadIdx.x;
    int e0 = rowp[n], e1 = rowp[n + 1];
    float a0 = 0.f, a1 = 0.f;
    int e = e0;
    for (; e + 1 < e1; e += 2) {
        unsigned p0 = ep[e], p1 = ep[e + 1];
        a0 += __half2float(__ushort_as_half((unsigned short)(p0 >> 16))) * tin[p0 & 0xFFFF];
        a1 += __half2float(__ushort_as_half((unsigned short)(p1 >> 16))) * tin[p1 & 0xFFFF];
    }
    if (e < e1) {
        unsigned p = ep[e];
        a0 += __half2float(__ushort_as_half((unsigned short)(p >> 16))) * tin[p & 0xFFFF];
    }
    float r = alpha * (a0 + a1);
    if (prev) r -= prev[n];
    tout[n] = r;
}

// ------- width-32 fp16 propagation: 8 lanes/node, lane = feature quad -------
__global__ __launch_bounds__(256) void k_prop32(const int* __restrict__ rowp,
                                                const unsigned* __restrict__ ep,
                                                const __half* __restrict__ tin,
                                                const __half* __restrict__ prev,
                                                __half* __restrict__ tout,
                                                float alpha) {
    int idx = blockIdx.x * 256 + threadIdx.x;
    int n = idx >> 3, j4 = (idx & 7) << 2;
    int e0 = rowp[n], e1 = rowp[n + 1];
    float a0 = 0.f, a1 = 0.f, a2 = 0.f, a3 = 0.f;
    float b0 = 0.f, b1 = 0.f, b2 = 0.f, b3 = 0.f;
    int e = e0;
    for (; e + 1 < e1; e += 2) {
        unsigned p0 = ep[e], p1 = ep[e + 1];
        float2 q0 = *(const float2*)(tin + ((p0 & 0xFFFFu) << 5) + j4);
        float2 q1 = *(const float2*)(tin + ((p1 & 0xFFFFu) << 5) + j4);
        float w0 = __half2float(__ushort_as_half((unsigned short)(p0 >> 16)));
        float w1 = __half2float(__ushort_as_half((unsigned short)(p1 >> 16)));
        float2 f00 = __half22float2(*(__half2*)&q0.x);
        float2 f01 = __half22float2(*(__half2*)&q0.y);
        float2 f10 = __half22float2(*(__half2*)&q1.x);
        float2 f11 = __half22float2(*(__half2*)&q1.y);
        a0 += w0 * f00.x; a1 += w0 * f00.y; a2 += w0 * f01.x; a3 += w0 * f01.y;
        b0 += w1 * f10.x; b1 += w1 * f10.y; b2 += w1 * f11.x; b3 += w1 * f11.y;
    }
    if (e < e1) {
        unsigned p = ep[e];
        float2 q = *(const float2*)(tin + ((p & 0xFFFFu) << 5) + j4);
        float w = __half2float(__ushort_as_half((unsigned short)(p >> 16)));
        float2 f0 = __half22float2(*(__half2*)&q.x);
        float2 f1 = __half22float2(*(__half2*)&q.y);
        a0 += w * f0.x; a1 += w * f0.y; a2 += w * f1.x; a3 += w * f1.y;
    }
    float r0 = alpha * (a0 + b0), r1 = alpha * (a1 + b1);
    float r2 = alpha * (a2 + b2), r3 = alpha * (a3 + b3);
    int o = (n << 5) + j4;
    if (prev) {
        float2 pq = *(const float2*)(prev + o);
        float2 p0 = __half22float2(*(__half2*)&pq.x);
        float2 p1 = __half22float2(*(__half2*)&pq.y);
        r0 -= p0.x; r1 -= p0.y; r2 -= p1.x; r3 -= p1.y;
    }
    float2 ov;
    *(__half2*)&ov.x = __floats2half2_rn(r0, r1);
    *(__half2*)&ov.y = __floats2half2_rn(r2, r3);
    *(float2*)(tout + o) = ov;
}

// ---------------- layer-1 combine: h = relu(x*W[0] + sum_k tx_k*W[k] + b) ---
__global__ __launch_bounds__(256) void k_comb1(const float* __restrict__ x,
                                               const float* __restrict__ txr,
                                               const float* __restrict__ W,
                                               const float* __restrict__ b,
                                               __half* __restrict__ hout) {
    int idx = blockIdx.x * 256 + threadIdx.x;
    int n = idx >> 5, j = idx & 31;
    float acc = b[j] + x[n] * W[j];
#pragma unroll
    for (int k = 1; k < KCH; ++k)
        acc += txr[(k - 1) * NN + n] * W[k * HID + j];
    hout[idx] = __float2half(fmaxf(acc, 0.f));
}

// ---------------- 32-wide combine (may write in place into tx slot 0) -------
__global__ __launch_bounds__(256) void k_comb32(const __half* tx,
                                                const float* __restrict__ W,
                                                const float* __restrict__ b,
                                                __half* hout,
                                                int relu) {
    __shared__ float Ws[KCH * HID * HID];
    int tid = threadIdx.x;
    for (int t = tid; t < KCH * HID * HID; t += 256) Ws[t] = W[t];
    __syncthreads();
    int idx = blockIdx.x * 256 + tid;
    int n = idx >> 5, j = idx & 31;
    int lane = tid & 63;
    int base_lane = lane & 32;
    float acc = b[j];
#pragma unroll
    for (int k = 0; k < KCH; ++k) {
        float vk = __half2float(tx[(size_t)k * NN * HID + (n << 5) + j]);
#pragma unroll
        for (int i = 0; i < HID; ++i) {
            float a = __shfl(vk, base_lane + i, 64);
            acc += a * Ws[(k * HID + i) * HID + j];
        }
    }
    acc = relu ? fmaxf(acc, 0.f) : acc;
    hout[idx] = __float2half(acc);
}

// ---------------- Wl fp32 -> fp16 padded rows ----------------
__global__ __launch_bounds__(256) void k_cvt(const float* __restrict__ Wl,
                                             __half* __restrict__ Wlh) {
    int m = blockIdx.x * 256 + threadIdx.x;
    const float* src = Wl + (size_t)m * OUTS;
    __half* dst = Wlh + (size_t)m * WLP;
#pragma unroll
    for (int o = 0; o < OUTS; ++o) dst[o] = __float2half(src[o]);
    dst[33] = __float2half(0.f);
    dst[34] = __float2half(0.f);
    dst[35] = __float2half(0.f);
}

// ---------------- readout ----------------
__global__ void k_initout(const float* __restrict__ bl, float* __restrict__ out) {
    int i = blockIdx.x * 64 + threadIdx.x;
    if (i < NG * OUTS) out[i] = bl[i % OUTS];
}

__global__ __launch_bounds__(256) void k_readout(const __half* __restrict__ h,
                                                 const __half* __restrict__ Wlh,
                                                 float* __restrict__ out) {
    int gp = blockIdx.x >> 7;
    int mc = blockIdx.x & 127;
    int tid = threadIdx.x;
    int g0 = gp * 2, g1 = g0 + 1;
    float acc0[OUTS], acc1[OUTS];
#pragma unroll
    for (int o = 0; o < OUTS; ++o) { acc0[o] = 0.f; acc1[o] = 0.f; }
    const __half* h0 = h + (size_t)g0 * GSZ;
    const __half* h1 = h + (size_t)g1 * GSZ;
    for (int it = 0; it < 8; ++it) {
        int m = mc * 2048 + it * 256 + tid;
        float hv0 = __half2float(h0[m]);
        float hv1 = __half2float(h1[m]);
        const __half2* rp = (const __half2*)(Wlh + (size_t)m * WLP);
        __half2 rw[17];
#pragma unroll
        for (int q = 0; q < 17; ++q) rw[q] = rp[q];
#pragma unroll
        for (int q = 0; q < 16; ++q) {
            float2 f = __half22float2(rw[q]);
            acc0[2 * q]     += hv0 * f.x;  acc1[2 * q]     += hv1 * f.x;
            acc0[2 * q + 1] += hv0 * f.y;  acc1[2 * q + 1] += hv1 * f.y;
        }
        float lw = __half2float(__low2half(rw[16]));
        acc0[32] += hv0 * lw;  acc1[32] += hv1 * lw;
    }
    __shared__ float red[4][2 * OUTS];
    int lane = tid & 63, w = tid >> 6;
#pragma unroll
    for (int o = 0; o < OUTS; ++o) {
        float v0 = acc0[o], v1 = acc1[o];
        for (int off = 32; off > 0; off >>= 1) {
            v0 += __shfl_down(v0, off, 64);
            v1 += __shfl_down(v1, off, 64);
        }
        if (lane == 0) { red[w][o] = v0; red[w][OUTS + o] = v1; }
    }
    __syncthreads();
    if (tid < 2 * OUTS) {
        float s = red[0][tid] + red[1][tid] + red[2][tid] + red[3][tid];
        int g = (tid < OUTS) ? g0 : g1;
        int o = (tid < OUTS) ? tid : tid - OUTS;
        atomicAdd(&out[g * OUTS + o], s);
    }
}

extern "C" void kernel_launch(void* const* d_in, const int* in_sizes, int n_in,
                              void* d_out, int out_size, void* d_ws, size_t ws_size,
                              hipStream_t stream) {
    const float* x  = (const float*)d_in[0];
    const int*   ei = (const int*)d_in[1];
    const float* W1 = (const float*)d_in[3];
    const float* b1 = (const float*)d_in[4];
    const float* W2 = (const float*)d_in[5];
    const float* b2 = (const float*)d_in[6];
    const float* W3 = (const float*)d_in[7];
    const float* b3 = (const float*)d_in[8];
    const float* Wl = (const float*)d_in[9];
    const float* bl = (const float*)d_in[10];
    float* out = (float*)d_out;

    char* ws = (char*)d_ws;
    size_t off = 0;
    auto alloc = [&](size_t bytes) -> void* {
        void* p = ws + off;
        off += (bytes + 255) & ~(size_t)255;
        return p;
    };
    unsigned char* pdeg = (unsigned char*)alloc((size_t)2 * SLICES * RSIZE);
    int*      bcnt   = (int*)alloc((size_t)128 * NBK * 4);
    int*      bbase  = (int*)alloc((size_t)257 * 4);
    int*      rowp   = (int*)alloc((size_t)(NN + 1) * 4);
    float*    dinv   = (float*)alloc((size_t)NN * 4);
    unsigned* bkt    = (unsigned*)alloc((size_t)EE * 4);
    unsigned* ep     = (unsigned*)alloc((size_t)EE * 4);
    float*    txw1   = (float*)alloc((size_t)4 * NN * 4);
    __half*   tx32   = (__half*)alloc((size_t)KCH * NN * HID * 2);
    __half*   hfin   = (__half*)alloc((size_t)NN * HID * 2);
    __half*   Wlh    = (__half*)alloc((size_t)GSZ * WLP * 2);

    // ---- CSR build (atomic-free) ----
    k_hist<<<128, 1024, 0, stream>>>(ei, pdeg);
    k_hreduce<<<64, 256, 0, stream>>>(pdeg, dinv);
    k_bcnt<<<128, 1024, 0, stream>>>(ei, bcnt);
    k_bscan<<<1, 256, 0, stream>>>(bcnt, bbase);
    k_bucket<<<128, 1024, 0, stream>>>(ei, bcnt, bkt);
    k_place<<<256, 512, 0, stream>>>(bkt, bbase, dinv, ep, rowp);
    k_cvt<<<GSZ / 256, 256, 0, stream>>>(Wl, Wlh);

    // ---- layer 1 (width-1, fp32 recurrence) ----
    float *t1 = txw1, *t2 = txw1 + NN, *t3 = txw1 + 2 * NN, *t4 = txw1 + 3 * NN;
    k_prop1<<<NN / 256, 256, 0, stream>>>(rowp, ep, x,  nullptr, t1, 1.f);
    k_prop1<<<NN / 256, 256, 0, stream>>>(rowp, ep, t1, x,       t2, 2.f);
    k_prop1<<<NN / 256, 256, 0, stream>>>(rowp, ep, t2, t1,      t3, 2.f);
    k_prop1<<<NN / 256, 256, 0, stream>>>(rowp, ep, t3, t2,      t4, 2.f);
    k_comb1<<<(NN * HID) / 256, 256, 0, stream>>>(x, txw1, W1, b1, tx32);

    const size_t S = (size_t)NN * HID;
    const int PG = (NN * 8) / 256;    // 2048 blocks, 8 lanes/node
    // ---- layer 2 ----
    k_prop32<<<PG, 256, 0, stream>>>(rowp, ep, tx32,         nullptr,      tx32 + 1 * S, 1.f);
    k_prop32<<<PG, 256, 0, stream>>>(rowp, ep, tx32 + 1 * S, tx32,         tx32 + 2 * S, 2.f);
    k_prop32<<<PG, 256, 0, stream>>>(rowp, ep, tx32 + 2 * S, tx32 + 1 * S, tx32 + 3 * S, 2.f);
    k_prop32<<<PG, 256, 0, stream>>>(rowp, ep, tx32 + 3 * S, tx32 + 2 * S, tx32 + 4 * S, 2.f);
    k_comb32<<<S / 256, 256, 0, stream>>>(tx32, W2, b2, tx32, 1);

    // ---- layer 3 (no relu) ----
    k_prop32<<<PG, 256, 0, stream>>>(rowp, ep, tx32,         nullptr,      tx32 + 1 * S, 1.f);
    k_prop32<<<PG, 256, 0, stream>>>(rowp, ep, tx32 + 1 * S, tx32,         tx32 + 2 * S, 2.f);
    k_prop32<<<PG, 256, 0, stream>>>(rowp, ep, tx32 + 2 * S, tx32 + 1 * S, tx32 + 3 * S, 2.f);
    k_prop32<<<PG, 256, 0, stream>>>(rowp, ep, tx32 + 3 * S, tx32 + 2 * S, tx32 + 4 * S, 2.f);
    k_comb32<<<S / 256, 256, 0, stream>>>(tx32, W3, b3, hfin, 0);

    // ---- readout ----
    k_initout<<<5, 64, 0, stream>>>(bl, out);
    k_readout<<<512, 256, 0, stream>>>(hfin, Wlh, out);
}

// Round 5
// 498.313 us; speedup vs baseline: 2.7229x; 1.2773x over previous
//
#include <hip/hip_runtime.h>
#include <hip/hip_fp16.h>

#define NN     65536    // total nodes
#define EE     2097152  // edges
#define HID    32
#define KCH    5
#define OUTS   33
#define NG     8
#define GSZ    262144   // INPUT_SIZE * HIDDEN per graph
#define WLP    36       // padded fp16 row length for Wl
#define SLICES 64       // edge slices for src histogram
#define RSIZE  32768    // counters per range (2 ranges cover 64K nodes)
#define BSL    16384    // edges per bucketing slice (128 slices)
#define NBK    256      // coarse buckets (dst >> 8)
#define STG    9472     // LDS staging capacity in k_place

typedef _Float16 half8 __attribute__((ext_vector_type(8)));
typedef float floatx4 __attribute__((ext_vector_type(4)));

// exclusive scan of sh[0..255] in place; whole block must call
__device__ __forceinline__ void exscan256(int tid, int* __restrict__ sh,
                                          int* __restrict__ wsc) {
    int v = 0, s = 0;
    if (tid < 256) {
        v = sh[tid];
        s = v;
        int lane = tid & 63;
        #pragma unroll
        for (int off = 1; off < 64; off <<= 1) {
            int t = __shfl_up(s, off, 64);
            if (lane >= off) s += t;
        }
        if (lane == 63) wsc[tid >> 6] = s;
    }
    __syncthreads();
    if (tid == 0) {
        int a = 0;
        #pragma unroll
        for (int i = 0; i < 4; ++i) { int t = wsc[i]; wsc[i] = a; a += t; }
    }
    __syncthreads();
    if (tid < 256) sh[tid] = s - v + wsc[tid >> 6];
    __syncthreads();
}

// ---------------- src out-degree histogram (LDS-privatized) -----------------
__global__ __launch_bounds__(1024) void k_hist(const int* __restrict__ ei,
                                               unsigned char* __restrict__ pdeg) {
    __shared__ unsigned cnt[RSIZE];
    int b = blockIdx.x;
    int r = (b >> 6) & 1, s = b & 63;
    const int* keys = ei + s * (EE / SLICES);
    unsigned char* pout = pdeg + (size_t)(r * SLICES + s) * RSIZE;
    int tid = threadIdx.x;
    for (int i = tid; i < RSIZE; i += 1024) cnt[i] = 0;
    __syncthreads();
    int lo = r * RSIZE, hi = lo + RSIZE;
    for (int i = tid; i < EE / SLICES; i += 1024) {
        int k = keys[i];
        if (k >= lo && k < hi) atomicAdd(&cnt[k - lo], 1u);
    }
    __syncthreads();
    unsigned* pout4 = (unsigned*)pout;
    for (int i = tid; i < RSIZE / 4; i += 1024) {
        unsigned c0 = cnt[4 * i], c1 = cnt[4 * i + 1];
        unsigned c2 = cnt[4 * i + 2], c3 = cnt[4 * i + 3];
        pout4[i] = c0 | (c1 << 8) | (c2 << 16) | (c3 << 24);
    }
}

__global__ __launch_bounds__(256) void k_hreduce(const unsigned char* __restrict__ pdeg,
                                                 float* __restrict__ dinv) {
    int t = blockIdx.x * 256 + threadIdx.x;
    int r = t >> 13, ql = t & 8191;
    const unsigned* base = (const unsigned*)(pdeg + (size_t)r * SLICES * RSIZE) + ql;
    unsigned s0 = 0, s1 = 0, s2 = 0, s3 = 0;
#pragma unroll 8
    for (int s = 0; s < SLICES; ++s) {
        unsigned v = base[s * (RSIZE / 4)];
        s0 += v & 0xFF; s1 += (v >> 8) & 0xFF; s2 += (v >> 16) & 0xFF; s3 += v >> 24;
    }
    int c = (r << 15) + 4 * ql;
    dinv[c]     = s0 ? 1.0f / sqrtf((float)s0) : 0.0f;
    dinv[c + 1] = s1 ? 1.0f / sqrtf((float)s1) : 0.0f;
    dinv[c + 2] = s2 ? 1.0f / sqrtf((float)s2) : 0.0f;
    dinv[c + 3] = s3 ? 1.0f / sqrtf((float)s3) : 0.0f;
}

// ---------------- per-(slice, bucket) dst counts ----------------------------
__global__ __launch_bounds__(1024) void k_bcnt(const int* __restrict__ ei,
                                               int* __restrict__ bcnt) {
    __shared__ int cnt[NBK];
    int s = blockIdx.x, tid = threadIdx.x;
    if (tid < NBK) cnt[tid] = 0;
    __syncthreads();
    const int* dsts = ei + EE + s * BSL;
    for (int i = tid; i < BSL; i += 1024)
        atomicAdd(&cnt[dsts[i] >> 8], 1);
    __syncthreads();
    if (tid < NBK) bcnt[s * NBK + tid] = cnt[tid];
}

__global__ __launch_bounds__(256) void k_bscan(int* __restrict__ bcnt,
                                               int* __restrict__ bbase) {
    __shared__ int tot[256];
    __shared__ int wsc[4];
    int b = threadIdx.x;
    int run = 0;
    for (int s = 0; s < 128; ++s) {
        int c = bcnt[s * NBK + b];
        bcnt[s * NBK + b] = run;
        run += c;
    }
    tot[b] = run;
    __syncthreads();
    exscan256(b, tot, wsc);
    bbase[b] = tot[b];
    if (b == 0) bbase[256] = EE;
    for (int s = 0; s < 128; ++s)
        bcnt[s * NBK + b] += tot[b];
}

// ---------------- coarse bucketing: LDS counting sort, coalesced flush ------
__global__ __launch_bounds__(1024) void k_bucket(const int* __restrict__ ei,
                                                 const int* __restrict__ boff,
                                                 unsigned* __restrict__ bkt) {
    __shared__ unsigned stage[BSL];
    __shared__ int cnt[NBK], cur[NBK], gbase[NBK];
    __shared__ int wsc[4];
    int s = blockIdx.x, tid = threadIdx.x;
    if (tid < NBK) cnt[tid] = 0;
    __syncthreads();
    const int* srcs = ei + s * BSL;
    const int* dsts = ei + EE + s * BSL;
    for (int i = tid; i < BSL; i += 1024)
        atomicAdd(&cnt[dsts[i] >> 8], 1);
    __syncthreads();
    if (tid < NBK) gbase[tid] = boff[s * NBK + tid];
    exscan256(tid, cnt, wsc);
    if (tid < NBK) cur[tid] = cnt[tid];
    __syncthreads();
    for (int i = tid; i < BSL; i += 1024) {
        int d = dsts[i];
        int pos = atomicAdd(&cur[d >> 8], 1);
        stage[pos] = (unsigned)srcs[i] | ((unsigned)d << 16);
    }
    __syncthreads();
    for (int j = tid; j < BSL; j += 1024) {
        unsigned rec = stage[j];
        int b = rec >> 24;
        bkt[gbase[b] + (j - cnt[b])] = rec;
    }
}

// ---------------- fine placement: exact CSR, packed ep, rowp ----------------
__global__ __launch_bounds__(512) void k_place(const unsigned* __restrict__ bkt,
                                               const int* __restrict__ bbase,
                                               const float* __restrict__ dinv,
                                               unsigned* __restrict__ ep,
                                               int* __restrict__ rowp) {
    __shared__ unsigned stage[STG];
    __shared__ int hist[NBK], cur[NBK];
    __shared__ float dl[NBK];
    __shared__ int wsc[4];
    int b = blockIdx.x, tid = threadIdx.x;
    int base = bbase[b], cnt = bbase[b + 1] - base;
    if (tid < NBK) { hist[tid] = 0; dl[tid] = dinv[b * NBK + tid]; }
    __syncthreads();
    const unsigned* recs = bkt + base;
    for (int i = tid; i < cnt; i += 512)
        atomicAdd(&hist[(recs[i] >> 16) & 255], 1);
    __syncthreads();
    exscan256(tid, hist, wsc);
    if (tid < NBK) {
        cur[tid] = hist[tid];
        rowp[b * NBK + tid] = base + hist[tid];
    }
    if (b == 0 && tid == 0) rowp[NN] = EE;
    __syncthreads();
    for (int i = tid; i < cnt; i += 512) {
        unsigned rec = recs[i];
        int srcv = rec & 0xFFFF;
        int dlow = (rec >> 16) & 255;
        float nr = -(dinv[srcv] * dl[dlow]);
        unsigned pk = (unsigned)srcv |
                      ((unsigned)__half_as_ushort(__float2half(nr)) << 16);
        int pos = atomicAdd(&cur[dlow], 1);
        if (pos < STG) stage[pos] = pk; else ep[base + pos] = pk;
    }
    __syncthreads();
    int lim = cnt < STG ? cnt : STG;
    for (int j = tid; j < lim; j += 512)
        ep[base + j] = stage[j];
}

// ---------------- width-1 propagation (layer 1, fp32) ----------------
__global__ __launch_bounds__(256) void k_prop1(const int* __restrict__ rowp,
                                               const unsigned* __restrict__ ep,
                                               const float* __restrict__ tin,
                                               const float* __restrict__ prev,
                                               float* __restrict__ tout,
                                               float alpha) {
    int n = blockIdx.x * 256 + threadIdx.x;
    int e0 = rowp[n], e1 = rowp[n + 1];
    float a0 = 0.f, a1 = 0.f;
    int e = e0;
    for (; e + 1 < e1; e += 2) {
        unsigned p0 = ep[e], p1 = ep[e + 1];
        a0 += __half2float(__ushort_as_half((unsigned short)(p0 >> 16))) * tin[p0 & 0xFFFF];
        a1 += __half2float(__ushort_as_half((unsigned short)(p1 >> 16))) * tin[p1 & 0xFFFF];
    }
    if (e < e1) {
        unsigned p = ep[e];
        a0 += __half2float(__ushort_as_half((unsigned short)(p >> 16))) * tin[p & 0xFFFF];
    }
    float r = alpha * (a0 + a1);
    if (prev) r -= prev[n];
    tout[n] = r;
}

// ------- width-32 fp16 propagation: 8 lanes/node, lane = feature quad -------
__global__ __launch_bounds__(256) void k_prop32(const int* __restrict__ rowp,
                                                const unsigned* __restrict__ ep,
                                                const __half* __restrict__ tin,
                                                const __half* __restrict__ prev,
                                                __half* __restrict__ tout,
                                                float alpha) {
    int idx = blockIdx.x * 256 + threadIdx.x;
    int n = idx >> 3, j4 = (idx & 7) << 2;
    int e0 = rowp[n], e1 = rowp[n + 1];
    float a0 = 0.f, a1 = 0.f, a2 = 0.f, a3 = 0.f;
    float b0 = 0.f, b1 = 0.f, b2 = 0.f, b3 = 0.f;
    int e = e0;
    for (; e + 1 < e1; e += 2) {
        unsigned p0 = ep[e], p1 = ep[e + 1];
        float2 q0 = *(const float2*)(tin + ((p0 & 0xFFFFu) << 5) + j4);
        float2 q1 = *(const float2*)(tin + ((p1 & 0xFFFFu) << 5) + j4);
        float w0 = __half2float(__ushort_as_half((unsigned short)(p0 >> 16)));
        float w1 = __half2float(__ushort_as_half((unsigned short)(p1 >> 16)));
        float2 f00 = __half22float2(*(__half2*)&q0.x);
        float2 f01 = __half22float2(*(__half2*)&q0.y);
        float2 f10 = __half22float2(*(__half2*)&q1.x);
        float2 f11 = __half22float2(*(__half2*)&q1.y);
        a0 += w0 * f00.x; a1 += w0 * f00.y; a2 += w0 * f01.x; a3 += w0 * f01.y;
        b0 += w1 * f10.x; b1 += w1 * f10.y; b2 += w1 * f11.x; b3 += w1 * f11.y;
    }
    if (e < e1) {
        unsigned p = ep[e];
        float2 q = *(const float2*)(tin + ((p & 0xFFFFu) << 5) + j4);
        float w = __half2float(__ushort_as_half((unsigned short)(p >> 16)));
        float2 f0 = __half22float2(*(__half2*)&q.x);
        float2 f1 = __half22float2(*(__half2*)&q.y);
        a0 += w * f0.x; a1 += w * f0.y; a2 += w * f1.x; a3 += w * f1.y;
    }
    float r0 = alpha * (a0 + b0), r1 = alpha * (a1 + b1);
    float r2 = alpha * (a2 + b2), r3 = alpha * (a3 + b3);
    int o = (n << 5) + j4;
    if (prev) {
        float2 pq = *(const float2*)(prev + o);
        float2 p0 = __half22float2(*(__half2*)&pq.x);
        float2 p1 = __half22float2(*(__half2*)&pq.y);
        r0 -= p0.x; r1 -= p0.y; r2 -= p1.x; r3 -= p1.y;
    }
    float2 ov;
    *(__half2*)&ov.x = __floats2half2_rn(r0, r1);
    *(__half2*)&ov.y = __floats2half2_rn(r2, r3);
    *(float2*)(tout + o) = ov;
}

// ---------------- layer-1 combine: h = relu(x*W[0] + sum_k tx_k*W[k] + b) ---
__global__ __launch_bounds__(256) void k_comb1(const float* __restrict__ x,
                                               const float* __restrict__ txr,
                                               const float* __restrict__ W,
                                               const float* __restrict__ b,
                                               __half* __restrict__ hout) {
    int idx = blockIdx.x * 256 + threadIdx.x;
    int n = idx >> 5, j = idx & 31;
    float acc = b[j] + x[n] * W[j];
#pragma unroll
    for (int k = 1; k < KCH; ++k)
        acc += txr[(k - 1) * NN + n] * W[k * HID + j];
    hout[idx] = __float2half(fmaxf(acc, 0.f));
}

// ---------------- W fp32 [k][i][j] -> fp16 transposed Wt [k][j][i] ----------
__global__ __launch_bounds__(256) void k_wcvt(const float* __restrict__ W,
                                              _Float16* __restrict__ Wt) {
    int t = blockIdx.x * 256 + threadIdx.x;   // 5120
    if (t < KCH * HID * HID) {
        int kc = t >> 10, rem = t & 1023, j = rem >> 5, i = rem & 31;
        Wt[t] = (_Float16)W[kc * 1024 + i * 32 + j];
    }
}

// ---------------- MFMA combine: h = act(sum_k tx_k @ W[k] + b) --------------
// GEMM M=65536, K=160 (5 planes x 32), N=32. One wave = 4 16-node tiles.
// A-frag: lane m=l&15 (node), kg=l>>4, 8 contiguous k -> global dwordx4.
// B-frag: Wt[k][j][i], lane n=l&15 (j within half), 8 contiguous i.
// C/D: node = nb + (l>>4)*4 + r, j = h*16 + (l&15).
__global__ __launch_bounds__(256) void k_comb32(const __half* tx,
                                                const _Float16* __restrict__ Wt,
                                                const float* __restrict__ b,
                                                __half* hout,
                                                int relu) {
    int tid = threadIdx.x;
    int lane = tid & 63;
    int wave = (blockIdx.x * 256 + tid) >> 6;   // 0..1023
    int m = lane & 15, kg = lane >> 4;
    half8 Bf[KCH][2];
#pragma unroll
    for (int kc = 0; kc < KCH; ++kc)
#pragma unroll
        for (int h = 0; h < 2; ++h)
            Bf[kc][h] = *(const half8*)(Wt + kc * 1024 + (h * 16 + m) * 32 + kg * 8);
    float bj0 = b[m], bj1 = b[16 + m];
    const size_t S = (size_t)NN * HID;
    const _Float16* txf = (const _Float16*)tx;
#pragma unroll
    for (int t = 0; t < 4; ++t) {
        int nb = (wave * 4 + t) << 4;
        floatx4 acc0 = {0.f, 0.f, 0.f, 0.f}, acc1 = {0.f, 0.f, 0.f, 0.f};
#pragma unroll
        for (int kc = 0; kc < KCH; ++kc) {
            half8 Af = *(const half8*)(txf + (size_t)kc * S + (size_t)(nb + m) * 32 + kg * 8);
            acc0 = __builtin_amdgcn_mfma_f32_16x16x32_f16(Af, Bf[kc][0], acc0, 0, 0, 0);
            acc1 = __builtin_amdgcn_mfma_f32_16x16x32_f16(Af, Bf[kc][1], acc1, 0, 0, 0);
        }
        int rowb = nb + kg * 4;
#pragma unroll
        for (int r = 0; r < 4; ++r) {
            float v0 = acc0[r] + bj0, v1 = acc1[r] + bj1;
            if (relu) { v0 = fmaxf(v0, 0.f); v1 = fmaxf(v1, 0.f); }
            hout[(size_t)(rowb + r) * 32 + m]      = __float2half(v0);
            hout[(size_t)(rowb + r) * 32 + 16 + m] = __float2half(v1);
        }
    }
}

// ---------------- Wl fp32 -> fp16 padded rows ----------------
__global__ __launch_bounds__(256) void k_cvt(const float* __restrict__ Wl,
                                             __half* __restrict__ Wlh) {
    int m = blockIdx.x * 256 + threadIdx.x;
    const float* src = Wl + (size_t)m * OUTS;
    __half* dst = Wlh + (size_t)m * WLP;
#pragma unroll
    for (int o = 0; o < OUTS; ++o) dst[o] = __float2half(src[o]);
    dst[33] = __float2half(0.f);
    dst[34] = __float2half(0.f);
    dst[35] = __float2half(0.f);
}

// ---------------- readout ----------------
__global__ void k_initout(const float* __restrict__ bl, float* __restrict__ out) {
    int i = blockIdx.x * 64 + threadIdx.x;
    if (i < NG * OUTS) out[i] = bl[i % OUTS];
}

__global__ __launch_bounds__(256) void k_readout(const __half* __restrict__ h,
                                                 const __half* __restrict__ Wlh,
                                                 float* __restrict__ out) {
    int gp = blockIdx.x >> 7;
    int mc = blockIdx.x & 127;
    int tid = threadIdx.x;
    int g0 = gp * 2, g1 = g0 + 1;
    float acc0[OUTS], acc1[OUTS];
#pragma unroll
    for (int o = 0; o < OUTS; ++o) { acc0[o] = 0.f; acc1[o] = 0.f; }
    const __half* h0 = h + (size_t)g0 * GSZ;
    const __half* h1 = h + (size_t)g1 * GSZ;
    for (int it = 0; it < 8; ++it) {
        int m = mc * 2048 + it * 256 + tid;
        float hv0 = __half2float(h0[m]);
        float hv1 = __half2float(h1[m]);
        const __half2* rp = (const __half2*)(Wlh + (size_t)m * WLP);
        __half2 rw[17];
#pragma unroll
        for (int q = 0; q < 17; ++q) rw[q] = rp[q];
#pragma unroll
        for (int q = 0; q < 16; ++q) {
            float2 f = __half22float2(rw[q]);
            acc0[2 * q]     += hv0 * f.x;  acc1[2 * q]     += hv1 * f.x;
            acc0[2 * q + 1] += hv0 * f.y;  acc1[2 * q + 1] += hv1 * f.y;
        }
        float lw = __half2float(__low2half(rw[16]));
        acc0[32] += hv0 * lw;  acc1[32] += hv1 * lw;
    }
    __shared__ float red[4][2 * OUTS];
    int lane = tid & 63, w = tid >> 6;
#pragma unroll
    for (int o = 0; o < OUTS; ++o) {
        float v0 = acc0[o], v1 = acc1[o];
        for (int off = 32; off > 0; off >>= 1) {
            v0 += __shfl_down(v0, off, 64);
            v1 += __shfl_down(v1, off, 64);
        }
        if (lane == 0) { red[w][o] = v0; red[w][OUTS + o] = v1; }
    }
    __syncthreads();
    if (tid < 2 * OUTS) {
        float s = red[0][tid] + red[1][tid] + red[2][tid] + red[3][tid];
        int g = (tid < OUTS) ? g0 : g1;
        int o = (tid < OUTS) ? tid : tid - OUTS;
        atomicAdd(&out[g * OUTS + o], s);
    }
}

extern "C" void kernel_launch(void* const* d_in, const int* in_sizes, int n_in,
                              void* d_out, int out_size, void* d_ws, size_t ws_size,
                              hipStream_t stream) {
    const float* x  = (const float*)d_in[0];
    const int*   ei = (const int*)d_in[1];
    const float* W1 = (const float*)d_in[3];
    const float* b1 = (const float*)d_in[4];
    const float* W2 = (const float*)d_in[5];
    const float* b2 = (const float*)d_in[6];
    const float* W3 = (const float*)d_in[7];
    const float* b3 = (const float*)d_in[8];
    const float* Wl = (const float*)d_in[9];
    const float* bl = (const float*)d_in[10];
    float* out = (float*)d_out;

    char* ws = (char*)d_ws;
    size_t off = 0;
    auto alloc = [&](size_t bytes) -> void* {
        void* p = ws + off;
        off += (bytes + 255) & ~(size_t)255;
        return p;
    };
    unsigned char* pdeg = (unsigned char*)alloc((size_t)2 * SLICES * RSIZE);
    int*      bcnt   = (int*)alloc((size_t)128 * NBK * 4);
    int*      bbase  = (int*)alloc((size_t)257 * 4);
    int*      rowp   = (int*)alloc((size_t)(NN + 1) * 4);
    float*    dinv   = (float*)alloc((size_t)NN * 4);
    unsigned* bkt    = (unsigned*)alloc((size_t)EE * 4);
    unsigned* ep     = (unsigned*)alloc((size_t)EE * 4);
    float*    txw1   = (float*)alloc((size_t)4 * NN * 4);
    __half*   tx32   = (__half*)alloc((size_t)KCH * NN * HID * 2);
    __half*   hfin   = (__half*)alloc((size_t)NN * HID * 2);
    __half*   Wlh    = (__half*)alloc((size_t)GSZ * WLP * 2);
    _Float16* Wt2    = (_Float16*)alloc((size_t)KCH * HID * HID * 2);
    _Float16* Wt3    = (_Float16*)alloc((size_t)KCH * HID * HID * 2);

    // ---- CSR build (atomic-free) ----
    k_hist<<<128, 1024, 0, stream>>>(ei, pdeg);
    k_hreduce<<<64, 256, 0, stream>>>(pdeg, dinv);
    k_bcnt<<<128, 1024, 0, stream>>>(ei, bcnt);
    k_bscan<<<1, 256, 0, stream>>>(bcnt, bbase);
    k_bucket<<<128, 1024, 0, stream>>>(ei, bcnt, bkt);
    k_place<<<256, 512, 0, stream>>>(bkt, bbase, dinv, ep, rowp);
    k_cvt<<<GSZ / 256, 256, 0, stream>>>(Wl, Wlh);
    k_wcvt<<<20, 256, 0, stream>>>(W2, Wt2);
    k_wcvt<<<20, 256, 0, stream>>>(W3, Wt3);

    // ---- layer 1 (width-1, fp32 recurrence) ----
    float *t1 = txw1, *t2 = txw1 + NN, *t3 = txw1 + 2 * NN, *t4 = txw1 + 3 * NN;
    k_prop1<<<NN / 256, 256, 0, stream>>>(rowp, ep, x,  nullptr, t1, 1.f);
    k_prop1<<<NN / 256, 256, 0, stream>>>(rowp, ep, t1, x,       t2, 2.f);
    k_prop1<<<NN / 256, 256, 0, stream>>>(rowp, ep, t2, t1,      t3, 2.f);
    k_prop1<<<NN / 256, 256, 0, stream>>>(rowp, ep, t3, t2,      t4, 2.f);
    k_comb1<<<(NN * HID) / 256, 256, 0, stream>>>(x, txw1, W1, b1, tx32);

    const size_t S = (size_t)NN * HID;
    const int PG = (NN * 8) / 256;    // 2048 blocks, 8 lanes/node
    // ---- layer 2 ----
    k_prop32<<<PG, 256, 0, stream>>>(rowp, ep, tx32,         nullptr,      tx32 + 1 * S, 1.f);
    k_prop32<<<PG, 256, 0, stream>>>(rowp, ep, tx32 + 1 * S, tx32,         tx32 + 2 * S, 2.f);
    k_prop32<<<PG, 256, 0, stream>>>(rowp, ep, tx32 + 2 * S, tx32 + 1 * S, tx32 + 3 * S, 2.f);
    k_prop32<<<PG, 256, 0, stream>>>(rowp, ep, tx32 + 3 * S, tx32 + 2 * S, tx32 + 4 * S, 2.f);
    k_comb32<<<256, 256, 0, stream>>>(tx32, Wt2, b2, tx32, 1);   // in-place slot 0

    // ---- layer 3 (no relu) ----
    k_prop32<<<PG, 256, 0, stream>>>(rowp, ep, tx32,         nullptr,      tx32 + 1 * S, 1.f);
    k_prop32<<<PG, 256, 0, stream>>>(rowp, ep, tx32 + 1 * S, tx32,         tx32 + 2 * S, 2.f);
    k_prop32<<<PG, 256, 0, stream>>>(rowp, ep, tx32 + 2 * S, tx32 + 1 * S, tx32 + 3 * S, 2.f);
    k_prop32<<<PG, 256, 0, stream>>>(rowp, ep, tx32 + 3 * S, tx32 + 2 * S, tx32 + 4 * S, 2.f);
    k_comb32<<<256, 256, 0, stream>>>(tx32, Wt3, b3, hfin, 0);

    // ---- readout ----
    k_initout<<<5, 64, 0, stream>>>(bl, out);
    k_readout<<<512, 256, 0, stream>>>(hfin, Wlh, out);
}

// Round 6
// 453.804 us; speedup vs baseline: 2.9900x; 1.0981x over previous
//
#include <hip/hip_runtime.h>
#include <hip/hip_fp16.h>

#define NN     65536    // total nodes
#define EE     2097152  // edges
#define HID    32
#define KCH    5
#define OUTS   33
#define NG     8
#define GSZ    262144   // INPUT_SIZE * HIDDEN per graph
#define WLP    36       // padded fp16 row length for Wl
#define SLICES 64       // edge slices for src histogram
#define RSIZE  32768    // counters per range (2 ranges cover 64K nodes)
#define BSL    16384    // edges per bucketing slice (128 slices)
#define NBK    256      // coarse buckets (dst >> 8)
#define STG    9472     // LDS staging capacity in k_place

typedef _Float16 half8 __attribute__((ext_vector_type(8)));
typedef float floatx4 __attribute__((ext_vector_type(4)));

// exclusive scan of sh[0..255] in place; whole block must call
__device__ __forceinline__ void exscan256(int tid, int* __restrict__ sh,
                                          int* __restrict__ wsc) {
    int v = 0, s = 0;
    if (tid < 256) {
        v = sh[tid];
        s = v;
        int lane = tid & 63;
        #pragma unroll
        for (int off = 1; off < 64; off <<= 1) {
            int t = __shfl_up(s, off, 64);
            if (lane >= off) s += t;
        }
        if (lane == 63) wsc[tid >> 6] = s;
    }
    __syncthreads();
    if (tid == 0) {
        int a = 0;
        #pragma unroll
        for (int i = 0; i < 4; ++i) { int t = wsc[i]; wsc[i] = a; a += t; }
    }
    __syncthreads();
    if (tid < 256) sh[tid] = s - v + wsc[tid >> 6];
    __syncthreads();
}

// ---------------- src out-degree histogram (LDS-privatized) -----------------
__global__ __launch_bounds__(1024) void k_hist(const int* __restrict__ ei,
                                               unsigned char* __restrict__ pdeg) {
    __shared__ unsigned cnt[RSIZE];
    int b = blockIdx.x;
    int r = (b >> 6) & 1, s = b & 63;
    const int* keys = ei + s * (EE / SLICES);
    unsigned char* pout = pdeg + (size_t)(r * SLICES + s) * RSIZE;
    int tid = threadIdx.x;
    for (int i = tid; i < RSIZE; i += 1024) cnt[i] = 0;
    __syncthreads();
    int lo = r * RSIZE, hi = lo + RSIZE;
    for (int i = tid; i < EE / SLICES; i += 1024) {
        int k = keys[i];
        if (k >= lo && k < hi) atomicAdd(&cnt[k - lo], 1u);
    }
    __syncthreads();
    unsigned* pout4 = (unsigned*)pout;
    for (int i = tid; i < RSIZE / 4; i += 1024) {
        unsigned c0 = cnt[4 * i], c1 = cnt[4 * i + 1];
        unsigned c2 = cnt[4 * i + 2], c3 = cnt[4 * i + 3];
        pout4[i] = c0 | (c1 << 8) | (c2 << 16) | (c3 << 24);
    }
}

__global__ __launch_bounds__(256) void k_hreduce(const unsigned char* __restrict__ pdeg,
                                                 float* __restrict__ dinv) {
    int t = blockIdx.x * 256 + threadIdx.x;
    int r = t >> 13, ql = t & 8191;
    const unsigned* base = (const unsigned*)(pdeg + (size_t)r * SLICES * RSIZE) + ql;
    unsigned s0 = 0, s1 = 0, s2 = 0, s3 = 0;
#pragma unroll 8
    for (int s = 0; s < SLICES; ++s) {
        unsigned v = base[s * (RSIZE / 4)];
        s0 += v & 0xFF; s1 += (v >> 8) & 0xFF; s2 += (v >> 16) & 0xFF; s3 += v >> 24;
    }
    int c = (r << 15) + 4 * ql;
    dinv[c]     = s0 ? 1.0f / sqrtf((float)s0) : 0.0f;
    dinv[c + 1] = s1 ? 1.0f / sqrtf((float)s1) : 0.0f;
    dinv[c + 2] = s2 ? 1.0f / sqrtf((float)s2) : 0.0f;
    dinv[c + 3] = s3 ? 1.0f / sqrtf((float)s3) : 0.0f;
}

// ---------------- per-(slice, bucket) dst counts ----------------------------
__global__ __launch_bounds__(1024) void k_bcnt(const int* __restrict__ ei,
                                               int* __restrict__ bcnt) {
    __shared__ int cnt[NBK];
    int s = blockIdx.x, tid = threadIdx.x;
    if (tid < NBK) cnt[tid] = 0;
    __syncthreads();
    const int* dsts = ei + EE + s * BSL;
    for (int i = tid; i < BSL; i += 1024)
        atomicAdd(&cnt[dsts[i] >> 8], 1);
    __syncthreads();
    if (tid < NBK) bcnt[s * NBK + tid] = cnt[tid];
}

__global__ __launch_bounds__(256) void k_bscan(int* __restrict__ bcnt,
                                               int* __restrict__ bbase) {
    __shared__ int tot[256];
    __shared__ int wsc[4];
    int b = threadIdx.x;
    int run = 0;
    for (int s = 0; s < 128; ++s) {
        int c = bcnt[s * NBK + b];
        bcnt[s * NBK + b] = run;
        run += c;
    }
    tot[b] = run;
    __syncthreads();
    exscan256(b, tot, wsc);
    bbase[b] = tot[b];
    if (b == 0) bbase[256] = EE;
    for (int s = 0; s < 128; ++s)
        bcnt[s * NBK + b] += tot[b];
}

// ---------------- coarse bucketing: LDS counting sort, coalesced flush ------
__global__ __launch_bounds__(1024) void k_bucket(const int* __restrict__ ei,
                                                 const int* __restrict__ boff,
                                                 unsigned* __restrict__ bkt) {
    __shared__ unsigned stage[BSL];
    __shared__ int cnt[NBK], cur[NBK], gbase[NBK];
    __shared__ int wsc[4];
    int s = blockIdx.x, tid = threadIdx.x;
    if (tid < NBK) cnt[tid] = 0;
    __syncthreads();
    const int* srcs = ei + s * BSL;
    const int* dsts = ei + EE + s * BSL;
    for (int i = tid; i < BSL; i += 1024)
        atomicAdd(&cnt[dsts[i] >> 8], 1);
    __syncthreads();
    if (tid < NBK) gbase[tid] = boff[s * NBK + tid];
    exscan256(tid, cnt, wsc);
    if (tid < NBK) cur[tid] = cnt[tid];
    __syncthreads();
    for (int i = tid; i < BSL; i += 1024) {
        int d = dsts[i];
        int pos = atomicAdd(&cur[d >> 8], 1);
        stage[pos] = (unsigned)srcs[i] | ((unsigned)d << 16);
    }
    __syncthreads();
    for (int j = tid; j < BSL; j += 1024) {
        unsigned rec = stage[j];
        int b = rec >> 24;
        bkt[gbase[b] + (j - cnt[b])] = rec;
    }
}

// ---------------- fine placement: exact CSR, packed ep, rowp ----------------
__global__ __launch_bounds__(512) void k_place(const unsigned* __restrict__ bkt,
                                               const int* __restrict__ bbase,
                                               const float* __restrict__ dinv,
                                               unsigned* __restrict__ ep,
                                               int* __restrict__ rowp) {
    __shared__ unsigned stage[STG];
    __shared__ int hist[NBK], cur[NBK];
    __shared__ float dl[NBK];
    __shared__ int wsc[4];
    int b = blockIdx.x, tid = threadIdx.x;
    int base = bbase[b], cnt = bbase[b + 1] - base;
    if (tid < NBK) { hist[tid] = 0; dl[tid] = dinv[b * NBK + tid]; }
    __syncthreads();
    const unsigned* recs = bkt + base;
    for (int i = tid; i < cnt; i += 512)
        atomicAdd(&hist[(recs[i] >> 16) & 255], 1);
    __syncthreads();
    exscan256(tid, hist, wsc);
    if (tid < NBK) {
        cur[tid] = hist[tid];
        rowp[b * NBK + tid] = base + hist[tid];
    }
    if (b == 0 && tid == 0) rowp[NN] = EE;
    __syncthreads();
    for (int i = tid; i < cnt; i += 512) {
        unsigned rec = recs[i];
        int srcv = rec & 0xFFFF;
        int dlow = (rec >> 16) & 255;
        float nr = -(dinv[srcv] * dl[dlow]);
        unsigned pk = (unsigned)srcv |
                      ((unsigned)__half_as_ushort(__float2half(nr)) << 16);
        int pos = atomicAdd(&cur[dlow], 1);
        if (pos < STG) stage[pos] = pk; else ep[base + pos] = pk;
    }
    __syncthreads();
    int lim = cnt < STG ? cnt : STG;
    for (int j = tid; j < lim; j += 512)
        ep[base + j] = stage[j];
}

// ------- width-1 propagation: 4 lanes/node, strided edges, shfl reduce ------
__global__ __launch_bounds__(256) void k_prop1(const int* __restrict__ rowp,
                                               const unsigned* __restrict__ ep,
                                               const float* __restrict__ tin,
                                               const float* __restrict__ prev,
                                               float* __restrict__ tout,
                                               float alpha) {
    int idx = blockIdx.x * 256 + threadIdx.x;
    int n = idx >> 2, l = idx & 3;
    int e0 = rowp[n], e1 = rowp[n + 1];
    float a = 0.f;
    for (int e = e0 + l; e < e1; e += 4) {
        unsigned p = ep[e];
        a += __half2float(__ushort_as_half((unsigned short)(p >> 16))) * tin[p & 0xFFFF];
    }
    a += __shfl_xor(a, 1, 64);
    a += __shfl_xor(a, 2, 64);
    if (l == 0) {
        float r = alpha * a;
        if (prev) r -= prev[n];
        tout[n] = r;
    }
}

// ---- width-32 fp16 propagation: 4 lanes/node, 16B gathers, 4-edge unroll ---
__global__ __launch_bounds__(256) void k_prop32(const int* __restrict__ rowp,
                                                const unsigned* __restrict__ ep,
                                                const __half* __restrict__ tin,
                                                const __half* __restrict__ prev,
                                                __half* __restrict__ tout,
                                                float alpha) {
    int idx = blockIdx.x * 256 + threadIdx.x;
    int n = idx >> 2, j8 = (idx & 3) << 3;
    int e0 = rowp[n], e1 = rowp[n + 1];
    const _Float16* tf = (const _Float16*)tin;
    float acc[8];
#pragma unroll
    for (int i = 0; i < 8; ++i) acc[i] = 0.f;
    int e = e0;
    int ea = (e0 + 3) & ~3;                 // align to 16B for uint4 meta loads
    if (ea > e1) ea = e1;
    for (; e < ea; ++e) {
        unsigned p = ep[e];
        half8 v = *(const half8*)(tf + ((p & 0xFFFFu) << 5) + j8);
        float w = __half2float(__ushort_as_half((unsigned short)(p >> 16)));
#pragma unroll
        for (int i = 0; i < 8; ++i) acc[i] += w * (float)v[i];
    }
    int e4 = e + ((e1 - e) & ~3);
    for (; e < e4; e += 4) {
        uint4 pp = *(const uint4*)(ep + e);
        half8 v0 = *(const half8*)(tf + ((pp.x & 0xFFFFu) << 5) + j8);
        half8 v1 = *(const half8*)(tf + ((pp.y & 0xFFFFu) << 5) + j8);
        half8 v2 = *(const half8*)(tf + ((pp.z & 0xFFFFu) << 5) + j8);
        half8 v3 = *(const half8*)(tf + ((pp.w & 0xFFFFu) << 5) + j8);
        float w0 = __half2float(__ushort_as_half((unsigned short)(pp.x >> 16)));
        float w1 = __half2float(__ushort_as_half((unsigned short)(pp.y >> 16)));
        float w2 = __half2float(__ushort_as_half((unsigned short)(pp.z >> 16)));
        float w3 = __half2float(__ushort_as_half((unsigned short)(pp.w >> 16)));
#pragma unroll
        for (int i = 0; i < 8; ++i)
            acc[i] += w0 * (float)v0[i] + w1 * (float)v1[i]
                    + w2 * (float)v2[i] + w3 * (float)v3[i];
    }
    for (; e < e1; ++e) {
        unsigned p = ep[e];
        half8 v = *(const half8*)(tf + ((p & 0xFFFFu) << 5) + j8);
        float w = __half2float(__ushort_as_half((unsigned short)(p >> 16)));
#pragma unroll
        for (int i = 0; i < 8; ++i) acc[i] += w * (float)v[i];
    }
    int o = (n << 5) + j8;
    half8 hr;
    if (prev) {
        half8 pv = *(const half8*)((const _Float16*)prev + o);
#pragma unroll
        for (int i = 0; i < 8; ++i) hr[i] = (_Float16)(alpha * acc[i] - (float)pv[i]);
    } else {
#pragma unroll
        for (int i = 0; i < 8; ++i) hr[i] = (_Float16)(alpha * acc[i]);
    }
    *(half8*)((_Float16*)tout + o) = hr;
}

// ---------------- layer-1 combine: h = relu(x*W[0] + sum_k tx_k*W[k] + b) ---
__global__ __launch_bounds__(256) void k_comb1(const float* __restrict__ x,
                                               const float* __restrict__ txr,
                                               const float* __restrict__ W,
                                               const float* __restrict__ b,
                                               __half* __restrict__ hout) {
    int idx = blockIdx.x * 256 + threadIdx.x;
    int n = idx >> 5, j = idx & 31;
    float acc = b[j] + x[n] * W[j];
#pragma unroll
    for (int k = 1; k < KCH; ++k)
        acc += txr[(k - 1) * NN + n] * W[k * HID + j];
    hout[idx] = __float2half(fmaxf(acc, 0.f));
}

// ---------------- W fp32 [k][i][j] -> fp16 transposed Wt [k][j][i] ----------
__global__ __launch_bounds__(256) void k_wcvt(const float* __restrict__ W,
                                              _Float16* __restrict__ Wt) {
    int t = blockIdx.x * 256 + threadIdx.x;   // 5120
    if (t < KCH * HID * HID) {
        int kc = t >> 10, rem = t & 1023, j = rem >> 5, i = rem & 31;
        Wt[t] = (_Float16)W[kc * 1024 + i * 32 + j];
    }
}

// ---------------- MFMA combine: h = act(sum_k tx_k @ W[k] + b) --------------
__global__ __launch_bounds__(256) void k_comb32(const __half* tx,
                                                const _Float16* __restrict__ Wt,
                                                const float* __restrict__ b,
                                                __half* hout,
                                                int relu) {
    int tid = threadIdx.x;
    int lane = tid & 63;
    int wave = (blockIdx.x * 256 + tid) >> 6;   // 0..1023
    int m = lane & 15, kg = lane >> 4;
    half8 Bf[KCH][2];
#pragma unroll
    for (int kc = 0; kc < KCH; ++kc)
#pragma unroll
        for (int h = 0; h < 2; ++h)
            Bf[kc][h] = *(const half8*)(Wt + kc * 1024 + (h * 16 + m) * 32 + kg * 8);
    float bj0 = b[m], bj1 = b[16 + m];
    const size_t S = (size_t)NN * HID;
    const _Float16* txf = (const _Float16*)tx;
#pragma unroll
    for (int t = 0; t < 4; ++t) {
        int nb = (wave * 4 + t) << 4;
        floatx4 acc0 = {0.f, 0.f, 0.f, 0.f}, acc1 = {0.f, 0.f, 0.f, 0.f};
#pragma unroll
        for (int kc = 0; kc < KCH; ++kc) {
            half8 Af = *(const half8*)(txf + (size_t)kc * S + (size_t)(nb + m) * 32 + kg * 8);
            acc0 = __builtin_amdgcn_mfma_f32_16x16x32_f16(Af, Bf[kc][0], acc0, 0, 0, 0);
            acc1 = __builtin_amdgcn_mfma_f32_16x16x32_f16(Af, Bf[kc][1], acc1, 0, 0, 0);
        }
        int rowb = nb + kg * 4;
#pragma unroll
        for (int r = 0; r < 4; ++r) {
            float v0 = acc0[r] + bj0, v1 = acc1[r] + bj1;
            if (relu) { v0 = fmaxf(v0, 0.f); v1 = fmaxf(v1, 0.f); }
            hout[(size_t)(rowb + r) * 32 + m]      = __float2half(v0);
            hout[(size_t)(rowb + r) * 32 + 16 + m] = __float2half(v1);
        }
    }
}

// -------- Wl fp32 -> fp16 padded rows, LDS-staged coalesced -----------------
// 2048 blocks x 256 thr; each block converts 128 rows (128*33 floats -> 128*36 halves)
__global__ __launch_bounds__(256) void k_cvt(const float* __restrict__ Wl,
                                             __half* __restrict__ Wlh) {
    __shared__ float s[128 * 33];
    int blk = blockIdx.x, tid = threadIdx.x;
    const float* src = Wl + (size_t)blk * 128 * 33;
    for (int t = tid; t < 128 * 33; t += 256) s[t] = src[t];
    __syncthreads();
    unsigned* dst = (unsigned*)(Wlh + (size_t)blk * 128 * WLP);
    for (int t = tid; t < 128 * 18; t += 256) {
        int row = t / 18, c2 = t - row * 18;
        int c0 = 2 * c2;
        float f0 = (c0 < 33) ? s[row * 33 + c0] : 0.f;
        float f1 = (c0 + 1 < 33) ? s[row * 33 + c0 + 1] : 0.f;
        __half2 h = __floats2half2_rn(f0, f1);
        dst[t] = *(unsigned*)&h;
    }
}

// ---------------- readout ----------------
__global__ void k_initout(const float* __restrict__ bl, float* __restrict__ out) {
    int i = blockIdx.x * 64 + threadIdx.x;
    if (i < NG * OUTS) out[i] = bl[i % OUTS];
}

__global__ __launch_bounds__(256) void k_readout(const __half* __restrict__ h,
                                                 const __half* __restrict__ Wlh,
                                                 float* __restrict__ out) {
    int gp = blockIdx.x >> 7;
    int mc = blockIdx.x & 127;
    int tid = threadIdx.x;
    int g0 = gp * 2, g1 = g0 + 1;
    float acc0[OUTS], acc1[OUTS];
#pragma unroll
    for (int o = 0; o < OUTS; ++o) { acc0[o] = 0.f; acc1[o] = 0.f; }
    const __half* h0 = h + (size_t)g0 * GSZ;
    const __half* h1 = h + (size_t)g1 * GSZ;
    for (int it = 0; it < 8; ++it) {
        int m = mc * 2048 + it * 256 + tid;
        float hv0 = __half2float(h0[m]);
        float hv1 = __half2float(h1[m]);
        const __half2* rp = (const __half2*)(Wlh + (size_t)m * WLP);
        __half2 rw[17];
#pragma unroll
        for (int q = 0; q < 17; ++q) rw[q] = rp[q];
#pragma unroll
        for (int q = 0; q < 16; ++q) {
            float2 f = __half22float2(rw[q]);
            acc0[2 * q]     += hv0 * f.x;  acc1[2 * q]     += hv1 * f.x;
            acc0[2 * q + 1] += hv0 * f.y;  acc1[2 * q + 1] += hv1 * f.y;
        }
        float lw = __half2float(__low2half(rw[16]));
        acc0[32] += hv0 * lw;  acc1[32] += hv1 * lw;
    }
    __shared__ float red[4][2 * OUTS];
    int lane = tid & 63, w = tid >> 6;
#pragma unroll
    for (int o = 0; o < OUTS; ++o) {
        float v0 = acc0[o], v1 = acc1[o];
        for (int off = 32; off > 0; off >>= 1) {
            v0 += __shfl_down(v0, off, 64);
            v1 += __shfl_down(v1, off, 64);
        }
        if (lane == 0) { red[w][o] = v0; red[w][OUTS + o] = v1; }
    }
    __syncthreads();
    if (tid < 2 * OUTS) {
        float s = red[0][tid] + red[1][tid] + red[2][tid] + red[3][tid];
        int g = (tid < OUTS) ? g0 : g1;
        int o = (tid < OUTS) ? tid : tid - OUTS;
        atomicAdd(&out[g * OUTS + o], s);
    }
}

extern "C" void kernel_launch(void* const* d_in, const int* in_sizes, int n_in,
                              void* d_out, int out_size, void* d_ws, size_t ws_size,
                              hipStream_t stream) {
    const float* x  = (const float*)d_in[0];
    const int*   ei = (const int*)d_in[1];
    const float* W1 = (const float*)d_in[3];
    const float* b1 = (const float*)d_in[4];
    const float* W2 = (const float*)d_in[5];
    const float* b2 = (const float*)d_in[6];
    const float* W3 = (const float*)d_in[7];
    const float* b3 = (const float*)d_in[8];
    const float* Wl = (const float*)d_in[9];
    const float* bl = (const float*)d_in[10];
    float* out = (float*)d_out;

    char* ws = (char*)d_ws;
    size_t off = 0;
    auto alloc = [&](size_t bytes) -> void* {
        void* p = ws + off;
        off += (bytes + 255) & ~(size_t)255;
        return p;
    };
    unsigned char* pdeg = (unsigned char*)alloc((size_t)2 * SLICES * RSIZE);
    int*      bcnt   = (int*)alloc((size_t)128 * NBK * 4);
    int*      bbase  = (int*)alloc((size_t)257 * 4);
    int*      rowp   = (int*)alloc((size_t)(NN + 1) * 4);
    float*    dinv   = (float*)alloc((size_t)NN * 4);
    unsigned* bkt    = (unsigned*)alloc((size_t)EE * 4);
    unsigned* ep     = (unsigned*)alloc((size_t)EE * 4);
    float*    txw1   = (float*)alloc((size_t)4 * NN * 4);
    __half*   tx32   = (__half*)alloc((size_t)KCH * NN * HID * 2);
    __half*   hfin   = (__half*)alloc((size_t)NN * HID * 2);
    __half*   Wlh    = (__half*)alloc((size_t)GSZ * WLP * 2);
    _Float16* Wt2    = (_Float16*)alloc((size_t)KCH * HID * HID * 2);
    _Float16* Wt3    = (_Float16*)alloc((size_t)KCH * HID * HID * 2);

    // ---- CSR build (atomic-free) ----
    k_hist<<<128, 1024, 0, stream>>>(ei, pdeg);
    k_hreduce<<<64, 256, 0, stream>>>(pdeg, dinv);
    k_bcnt<<<128, 1024, 0, stream>>>(ei, bcnt);
    k_bscan<<<1, 256, 0, stream>>>(bcnt, bbase);
    k_bucket<<<128, 1024, 0, stream>>>(ei, bcnt, bkt);
    k_place<<<256, 512, 0, stream>>>(bkt, bbase, dinv, ep, rowp);
    k_cvt<<<2048, 256, 0, stream>>>(Wl, Wlh);
    k_wcvt<<<20, 256, 0, stream>>>(W2, Wt2);
    k_wcvt<<<20, 256, 0, stream>>>(W3, Wt3);

    // ---- layer 1 (width-1, fp32 recurrence) ----
    float *t1 = txw1, *t2 = txw1 + NN, *t3 = txw1 + 2 * NN, *t4 = txw1 + 3 * NN;
    k_prop1<<<NN * 4 / 256, 256, 0, stream>>>(rowp, ep, x,  nullptr, t1, 1.f);
    k_prop1<<<NN * 4 / 256, 256, 0, stream>>>(rowp, ep, t1, x,       t2, 2.f);
    k_prop1<<<NN * 4 / 256, 256, 0, stream>>>(rowp, ep, t2, t1,      t3, 2.f);
    k_prop1<<<NN * 4 / 256, 256, 0, stream>>>(rowp, ep, t3, t2,      t4, 2.f);
    k_comb1<<<(NN * HID) / 256, 256, 0, stream>>>(x, txw1, W1, b1, tx32);

    const size_t S = (size_t)NN * HID;
    const int PG = (NN * 4) / 256;    // 1024 blocks, 4 lanes/node
    // ---- layer 2 ----
    k_prop32<<<PG, 256, 0, stream>>>(rowp, ep, tx32,         nullptr,      tx32 + 1 * S, 1.f);
    k_prop32<<<PG, 256, 0, stream>>>(rowp, ep, tx32 + 1 * S, tx32,         tx32 + 2 * S, 2.f);
    k_prop32<<<PG, 256, 0, stream>>>(rowp, ep, tx32 + 2 * S, tx32 + 1 * S, tx32 + 3 * S, 2.f);
    k_prop32<<<PG, 256, 0, stream>>>(rowp, ep, tx32 + 3 * S, tx32 + 2 * S, tx32 + 4 * S, 2.f);
    k_comb32<<<256, 256, 0, stream>>>(tx32, Wt2, b2, tx32, 1);   // in-place slot 0

    // ---- layer 3 (no relu) ----
    k_prop32<<<PG, 256, 0, stream>>>(rowp, ep, tx32,         nullptr,      tx32 + 1 * S, 1.f);
    k_prop32<<<PG, 256, 0, stream>>>(rowp, ep, tx32 + 1 * S, tx32,         tx32 + 2 * S, 2.f);
    k_prop32<<<PG, 256, 0, stream>>>(rowp, ep, tx32 + 2 * S, tx32 + 1 * S, tx32 + 3 * S, 2.f);
    k_prop32<<<PG, 256, 0, stream>>>(rowp, ep, tx32 + 3 * S, tx32 + 2 * S, tx32 + 4 * S, 2.f);
    k_comb32<<<256, 256, 0, stream>>>(tx32, Wt3, b3, hfin, 0);

    // ---- readout ----
    k_initout<<<5, 64, 0, stream>>>(bl, out);
    k_readout<<<512, 256, 0, stream>>>(hfin, Wlh, out);
}